// Round 10
// baseline (454.485 us; speedup 1.0000x reference)
//
#include <hip/hip_runtime.h>

// ---------------------------------------------------------------------------
// DensityEstimator: 3-layer neural spline flow inverse log-prob.
// R15 (from R14 = 413.6us):
//  (1) zodd_transpose fused into gemm_lu: odd C cols staged in reused-LDS
//      T[64][130] (33KB), exported coalesced to z2oddT. -3 dispatches.
//  (2) z2 -> compact even-col z2e[4096][276] f32 (half the write traffic;
//      ident reads become contiguous).
//  (3) knot table transposed kT[43][825] (R12 change, reverted unblamed):
//      ident knot loads wave-contiguous instead of 43x 64-line gathers.
//  (4) Lmb/UpTb pad-zeroing folded into build_L -> 2 fewer memset nodes.
//  wo_spline/resnet/compose-gemm unchanged from R14.
// ---------------------------------------------------------------------------

#define D_DIM 550
#define D_PAD 576
#define N_PAD_A 640
#define F_DIM 275
#define F_PAD 320
#define FP_HALF 288            // D_PAD/2
#define FE_PAD 276             // compact even-col z2e row stride
#define HID_DIM 128
#define OUT_DIM 6325
#define OUT_PAD 6400
#define FT_PAD 276
#define WO24_ROWS (FT_PAD*24)  // 6624
#define WO_GX (WO24_ROWS/48)   // 138 col-blocks (48 cols = 2 features)
#define KT_G (3*F_DIM)         // 825
#define B_ROWS 4096
#define NBINS 8
#define TB_C 3.0f
#define MINB_C 0.001f
#define MIND_C 0.001f
#define DCONST_C 0.53974233f
#define LUEPS_C 0.001f
#define RSQRT_HID 0.08838834764831845f

typedef unsigned short ushort_t;
typedef __attribute__((ext_vector_type(8))) short short8;
typedef __attribute__((ext_vector_type(8))) unsigned short ushort8;
typedef __attribute__((ext_vector_type(4))) float f32x4;

__device__ __forceinline__ ushort_t f2bf(float f){
    union{float f; unsigned u;} v; v.f = f;
    unsigned r = v.u + 0x7fffu + ((v.u>>16)&1u);
    return (ushort_t)(r>>16);
}
__device__ __forceinline__ float bf2f(ushort_t h){
    union{unsigned u; float f;} v; v.u = ((unsigned)h)<<16;
    return v.f;
}
__device__ __forceinline__ float softplusf(float x){
    return fmaxf(x, 0.f) + __logf(1.f + __expf(-fabsf(x)));
}

__device__ __forceinline__ void knots_from_u(const float* u, float* c, float* w){
    float m = u[0];
#pragma unroll
    for(int k=1;k<NBINS;k++) m = fmaxf(m, u[k]);
    float e[NBINS]; float s = 0.f;
#pragma unroll
    for(int k=0;k<NBINS;k++){ e[k] = __expf(u[k]-m); s += e[k]; }
    float inv = 1.f/s;
    float cum = 0.f;
    c[0] = -TB_C;
#pragma unroll
    for(int k=0;k<NBINS;k++){
        float v = MINB_C + (1.f - MINB_C*(float)NBINS)*e[k]*inv;
        cum += v;
        c[k+1] = 2.f*TB_C*cum - TB_C;
    }
    c[NBINS] = TB_C;
#pragma unroll
    for(int k=0;k<NBINS;k++) w[k] = c[k+1]-c[k];
}

__device__ __forceinline__ void rqs_inv(float x,
                                        const float* cw, const float* w,
                                        const float* ch, const float* h,
                                        const float* d,
                                        float& out, float& ld){
    bool inside = (x >= -TB_C) && (x <= TB_C);
    float xi = fminf(fmaxf(x, -TB_C), TB_C);
    int idx = 0;
#pragma unroll
    for(int j=1;j<NBINS;j++) idx += (xi >= ch[j]) ? 1 : 0;
    float icw=cw[0], iw=w[0], ich=ch[0], ih=h[0], d0=d[0], d1=d[1];
#pragma unroll
    for(int j=1;j<NBINS;j++){
        if(idx==j){ icw=cw[j]; iw=w[j]; ich=ch[j]; ih=h[j]; d0=d[j]; d1=d[j+1]; }
    }
    float delta = ih/iw;
    float t  = xi - ich;
    float s  = d0 + d1 - 2.f*delta;
    float a  = t*s + ih*(delta - d0);
    float b  = ih*d0 - t*s;
    float c  = -delta*t;
    float disc = b*b - 4.f*a*c;
    float root = 2.f*c / (-b - sqrtf(fmaxf(disc, 0.f)));
    float o  = root*iw + icw;
    float tm = root*(1.f-root);
    float den  = delta + s*tm;
    float dnum = delta*delta*(d1*root*root + 2.f*delta*tm + d0*(1.f-root)*(1.f-root));
    float l = 2.f*__logf(den) - __logf(dnum);
    out = inside ? o : x;
    ld  = inside ? l : 0.f;
}

// --------------------------- setup kernels ---------------------------------

// Transposed knot table: kT[k][g], k<43, g = layer*275 + feature.
__global__ void build_knots_kernel(const float* __restrict__ uw_u,
                                   const float* __restrict__ uh_u,
                                   const float* __restrict__ ud_u,
                                   float* __restrict__ kT){
    int g = blockIdx.x*blockDim.x + threadIdx.x;
    if(g >= KT_G) return;
    float c[9], w[8];
    knots_from_u(uw_u + (size_t)g*8, c, w);
#pragma unroll
    for(int k=0;k<9;k++) kT[(size_t)k*KT_G + g] = c[k];
#pragma unroll
    for(int k=0;k<8;k++) kT[(size_t)(9+k)*KT_G + g] = w[k];
    knots_from_u(uh_u + (size_t)g*8, c, w);
#pragma unroll
    for(int k=0;k<9;k++) kT[(size_t)(17+k)*KT_G + g] = c[k];
#pragma unroll
    for(int k=0;k<8;k++) kT[(size_t)(26+k)*KT_G + g] = w[k];
    float dend = MIND_C + softplusf(DCONST_C);
    kT[(size_t)34*KT_G + g] = dend;
    kT[(size_t)42*KT_G + g] = dend;
    const float* ud = ud_u + (size_t)g*7;
#pragma unroll
    for(int k=0;k<7;k++) kT[(size_t)(35+k)*KT_G + g] = MIND_C + softplusf(ud[k]);
}

__global__ void logdiag_kernel(const float* __restrict__ lu_ud, float* __restrict__ outv){
    int tid = threadIdx.x;
    float s = 0.f;
    for(int k=tid; k<3*D_DIM; k+=256) s += __logf(softplusf(lu_ud[k]) + LUEPS_C);
#pragma unroll
    for(int o=32;o>0;o>>=1) s += __shfl_down(s, o);
    __shared__ float sm[4];
    if((tid&63)==0) sm[tid>>6]=s;
    __syncthreads();
    if(tid==0) outv[0] = sm[0]+sm[1]+sm[2]+sm[3];
}

// L matrix incl. pad rows/cols (drops Lmb memset); also zeroes UpTb pad
// rows 550..639 (drops UpTb memset; build_UT only writes perm rows < 550).
__global__ void build_L_bf16(const float* __restrict__ lower,
                             ushort_t* __restrict__ Lmb,
                             ushort_t* __restrict__ UpTb){
    int l = blockIdx.z;
    lower += (size_t)l*D_DIM*D_DIM;
    Lmb += (size_t)l*N_PAD_A*D_PAD;
    UpTb += (size_t)l*N_PAD_A*D_PAD;
    int k = blockIdx.x*blockDim.x + threadIdx.x;
    int j = blockIdx.y;
    if(k >= D_PAD) return;
    float lv = 0.f;
    if(j < D_DIM && k < D_DIM)
        lv = (j>k) ? lower[(size_t)j*D_DIM+k] : (j==k ? 1.f : 0.f);
    Lmb[(size_t)j*D_PAD+k] = f2bf(lv);
    if(j >= D_DIM) UpTb[(size_t)j*D_PAD+k] = 0;
}

// U^T with perm rows: 32x32 LDS transpose -> line-coalesced perm-row writes.
__global__ void build_UT_bf16(const float* __restrict__ upper,
                              const float* __restrict__ ud,
                              const int* __restrict__ perm,
                              ushort_t* __restrict__ UpTb){
    int l = blockIdx.z;
    upper += (size_t)l*D_DIM*D_DIM; ud += (size_t)l*D_DIM; perm += (size_t)l*D_DIM;
    UpTb += (size_t)l*N_PAD_A*D_PAD;
    __shared__ float t[32][33];
    int j0 = blockIdx.x*32, k0 = blockIdx.y*32;
    int tx = threadIdx.x, ty = threadIdx.y;
#pragma unroll
    for(int i=0;i<32;i+=8){
        int j = j0+ty+i, k = k0+tx;
        float uv = 0.f;
        if(j<D_DIM && k<D_DIM){
            if(j<k)       uv = upper[(size_t)j*D_DIM+k];
            else if(j==k) uv = softplusf(ud[k]) + LUEPS_C;
        }
        t[ty+i][tx] = uv;
    }
    __syncthreads();
#pragma unroll
    for(int i=0;i<32;i+=8){
        int k = k0+ty+i, j = j0+tx;
        if(k<D_DIM)
            UpTb[(size_t)perm[k]*D_PAD + j] = f2bf(t[tx][ty+i]);
    }
}

__global__ void convert_pad(const float* __restrict__ in, ushort_t* __restrict__ out,
                            int M, int K, int Mpad, int Kpad){
    int idx = blockIdx.x*256 + threadIdx.x;
    if(idx >= Mpad*Kpad) return;
    int r = idx / Kpad, c = idx - r*Kpad;
    float v = (r<M && c<K) ? in[(size_t)r*K+c] : 0.f;
    out[idx] = f2bf(v);
}

template<int REMAP>
__global__ void transpose_convert(const float* __restrict__ in, ushort_t* __restrict__ out,
                                  int K, int N, int Kpad, int Npad, long s_in, long s_out){
    in += (size_t)blockIdx.z*s_in; out += (size_t)blockIdx.z*s_out;
    __shared__ float t[32][33];
    int kb = blockIdx.x*32, nb = blockIdx.y*32;
    int tx = threadIdx.x, ty = threadIdx.y;
#pragma unroll
    for(int i=0;i<32;i+=8){
        int k = kb+ty+i, n = nb+tx;
        t[ty+i][tx] = (k<K && n<N) ? in[(size_t)k*N+n] : 0.f;
    }
    __syncthreads();
#pragma unroll
    for(int i=0;i<32;i+=8){
        int n = nb+ty+i, k = kb+tx;
        if(REMAP){
            if(n < OUT_DIM && k < Kpad){
                int f = n/23, j = n - 23*f;
                out[(size_t)(f*24+j)*Kpad+k] = f2bf(t[tx][ty+i]);
            }
        } else if(n<Npad && k<Kpad){
            out[(size_t)n*Kpad+k] = f2bf(t[tx][ty+i]);
        }
    }
}

__global__ void reorder_bias(const float* __restrict__ bo, float* __restrict__ bo2){
    int idx = blockIdx.x*256 + threadIdx.x;
    if(idx >= 3*OUT_DIM) return;
    int l = idx/OUT_DIM, n = idx%OUT_DIM;
    int f = n/23, j = n - 23*f;
    bo2[(size_t)l*WO24_ROWS + f*24 + j] = bo[idx];
}

// ------------------------------ bf16 MFMA gemm -----------------------------
// 128x128, bf16 out — used only for the LU-compose setup gemm.
__global__ __launch_bounds__(256)
void gemm_mfma_bf(const ushort_t* __restrict__ A, const ushort_t* __restrict__ Bt,
                  const float* __restrict__ bias, ushort_t* __restrict__ C,
                  int M, int N, int Kpad, long sA, long sB, long sC){
    A  += (size_t)blockIdx.z*sA;
    Bt += (size_t)blockIdx.z*sB;
    C  += (size_t)blockIdx.z*sC;
    __shared__ ushort_t As[128][72];
    __shared__ ushort_t Bs[128][72];
    int tid = threadIdx.x;
    int row0 = blockIdx.y*128, col0 = blockIdx.x*128;
    int wave = tid>>6, lane = tid&63;
    int wm = wave&1, wn = wave>>1;
    int lm = lane&15, quad = lane>>4;
    f32x4 acc[4][4] = {};
    for(int k0=0; k0<Kpad; k0+=64){
#pragma unroll
        for(int it=0; it<4; it++){
            int c = tid + it*256;
            int r = c>>3, c8 = (c&7)*8;
            *(ushort8*)&As[r][c8] = *(const ushort8*)(A + (size_t)(row0+r)*Kpad + k0 + c8);
            *(ushort8*)&Bs[r][c8] = *(const ushort8*)(Bt + (size_t)(col0+r)*Kpad + k0 + c8);
        }
        __syncthreads();
#pragma unroll
        for(int ks=0; ks<2; ks++){
            short8 af[4], bfr[4];
#pragma unroll
            for(int i=0;i<4;i++){
                af[i]  = *(const short8*)&As[wm*64 + i*16 + lm][ks*32 + quad*8];
                bfr[i] = *(const short8*)&Bs[wn*64 + i*16 + lm][ks*32 + quad*8];
            }
#pragma unroll
            for(int i=0;i<4;i++)
#pragma unroll
                for(int j=0;j<4;j++)
                    acc[i][j] = __builtin_amdgcn_mfma_f32_16x16x32_bf16(af[i], bfr[j], acc[i][j], 0, 0, 0);
        }
        __syncthreads();
    }
#pragma unroll
    for(int i=0;i<4;i++){
        int rbase = row0 + wm*64 + i*16 + quad*4;
#pragma unroll
        for(int j=0;j<4;j++){
            int gc = col0 + wn*64 + j*16 + lm;
            if(gc >= N) continue;
            float bv = bias[gc];
#pragma unroll
            for(int r=0;r<4;r++)
                C[(size_t)(rbase+r)*N+gc] = f2bf(acc[i][j][r] + bv);
        }
    }
}

// ---------------- LU-apply gemm + fused odd-col transposed export ----------
// C tile 128x128. Even cols (gc<550) -> compact z2e[row][fe] f32 (fe=gc/2).
// Odd cols -> staged in reused-LDS T[64][130] f32, exported coalesced to
// z2oddT[f][row]. Replaces gemm_mfma<0> + zodd_transpose.
__global__ __launch_bounds__(256)
void gemm_lu(const ushort_t* __restrict__ A, const ushort_t* __restrict__ Bt,
             const float* __restrict__ bias,
             float* __restrict__ z2e, float* __restrict__ z2oddT){
    __shared__ __align__(16) char smem[128*72*2*2];   // 36864B
    ushort_t (*As)[72] = (ushort_t(*)[72])smem;
    ushort_t (*Bs)[72] = (ushort_t(*)[72])(smem + 128*72*2);
    float (*T)[130] = (float(*)[130])smem;            // 64x130 f32 = 33280B
    int tid = threadIdx.x;
    int row0 = blockIdx.y*128, col0 = blockIdx.x*128;
    int wave = tid>>6, lane = tid&63;
    int wm = wave&1, wn = wave>>1;
    int lm = lane&15, quad = lane>>4;
    f32x4 acc[4][4] = {};
    for(int k0=0; k0<D_PAD; k0+=64){
#pragma unroll
        for(int it=0; it<4; it++){
            int c = tid + it*256;
            int r = c>>3, c8 = (c&7)*8;
            *(ushort8*)&As[r][c8] = *(const ushort8*)(A + (size_t)(row0+r)*D_PAD + k0 + c8);
            *(ushort8*)&Bs[r][c8] = *(const ushort8*)(Bt + (size_t)(col0+r)*D_PAD + k0 + c8);
        }
        __syncthreads();
#pragma unroll
        for(int ks=0; ks<2; ks++){
            short8 af[4], bfr[4];
#pragma unroll
            for(int i=0;i<4;i++){
                af[i]  = *(const short8*)&As[wm*64 + i*16 + lm][ks*32 + quad*8];
                bfr[i] = *(const short8*)&Bs[wn*64 + i*16 + lm][ks*32 + quad*8];
            }
#pragma unroll
            for(int i=0;i<4;i++)
#pragma unroll
                for(int j=0;j<4;j++)
                    acc[i][j] = __builtin_amdgcn_mfma_f32_16x16x32_bf16(af[i], bfr[j], acc[i][j], 0, 0, 0);
        }
        __syncthreads();
    }
    // Epilogue: even cols -> z2e; odd cols -> LDS T (then coalesced export).
    bool oddlane = (lm & 1);
#pragma unroll
    for(int j=0;j<4;j++){
        int cl = wn*64 + j*16 + lm;
        int gc = col0 + cl;
        float bv = (gc < D_DIM) ? bias[gc] : 0.f;
#pragma unroll
        for(int i=0;i<4;i++){
            int rl = wm*64 + i*16 + quad*4;
#pragma unroll
            for(int r=0;r<4;r++){
                float v = acc[i][j][r] + bv;
                if(oddlane){
                    T[cl>>1][rl+r] = v;
                } else if(gc < D_DIM){
                    z2e[(size_t)(row0+rl+r)*FE_PAD + (gc>>1)] = v;
                }
            }
        }
    }
    __syncthreads();
    int f0 = col0 >> 1;
#pragma unroll
    for(int it=0; it<32; it++){
        int idx = tid + it*256;
        int oc = idx >> 7, row = idx & 127;
        int f = f0 + oc;
        if(f < FP_HALF)
            z2oddT[(size_t)f*B_ROWS + row0 + row] = T[oc][row];
    }
}

// ------------------------------ fused resnet -------------------------------
// 16 rows/block, grid 256. No LDS weight staging (L2->reg, prefetched).
__global__ __launch_bounds__(256)
void resnet_fused(const ushort_t* __restrict__ identb,
                  const ushort_t* __restrict__ WiT,
                  const float* __restrict__ bi,
                  const ushort_t* __restrict__ WbT,
                  const float* __restrict__ bb,
                  ushort_t* __restrict__ tb){
    __shared__ ushort_t As2[16][136];
    int tid = threadIdx.x, wave = tid>>6, lane = tid&63;
    int lm = lane&15, quad = lane>>4;
    int r0 = blockIdx.x*16;
    int arow = r0 + lm;
    f32x4 cur[2] = {};
    f32x4 tsv[2];
    for(int k0=0; k0<F_PAD; k0+=64){
        const ushort_t* ap = identb + (size_t)arow*F_PAD + k0 + quad*8;
        short8 af0 = *(const short8*)(ap);
        short8 af1 = *(const short8*)(ap + 32);
#pragma unroll
        for(int jj=0;jj<2;jj++){
            int n = (wave*2+jj)*16 + lm;
            const ushort_t* wp = WiT + (size_t)n*F_PAD + k0 + quad*8;
            short8 b0 = *(const short8*)(wp);
            short8 b1 = *(const short8*)(wp + 32);
            cur[jj] = __builtin_amdgcn_mfma_f32_16x16x32_bf16(af0, b0, cur[jj], 0, 0, 0);
            cur[jj] = __builtin_amdgcn_mfma_f32_16x16x32_bf16(af1, b1, cur[jj], 0, 0, 0);
        }
    }
#pragma unroll
    for(int jj=0;jj<2;jj++){
        float bv = bi[(wave*2+jj)*16 + lm];
#pragma unroll
        for(int r=0;r<4;r++) cur[jj][r] += bv;
        tsv[jj] = cur[jj];
    }
    short8 wA[2][4], wB[2][4];
#pragma unroll
    for(int jj=0;jj<2;jj++){
        int n = (wave*2+jj)*16 + lm;
        const ushort_t* wp = WbT + (size_t)n*128 + quad*8;
#pragma unroll
        for(int ks=0;ks<4;ks++) wA[jj][ks] = *(const short8*)(wp + ks*32);
    }
#pragma unroll
    for(int st=0; st<4; st++){
        __syncthreads();
#pragma unroll
        for(int jj=0;jj<2;jj++)
#pragma unroll
            for(int r=0;r<4;r++)
                As2[quad*4 + r][(wave*2+jj)*16 + lm] = f2bf(fmaxf(cur[jj][r], 0.f));
        if(st < 3){
#pragma unroll
            for(int jj=0;jj<2;jj++){
                int n = (wave*2+jj)*16 + lm;
                const ushort_t* wp = WbT + (size_t)(st+1)*128*128 + (size_t)n*128 + quad*8;
#pragma unroll
                for(int ks=0;ks<4;ks++){
                    if(st & 1) wA[jj][ks] = *(const short8*)(wp + ks*32);
                    else       wB[jj][ks] = *(const short8*)(wp + ks*32);
                }
            }
        }
        __syncthreads();
        short8 af[4];
#pragma unroll
        for(int ks=0;ks<4;ks++) af[ks] = *(const short8*)&As2[lm][ks*32 + quad*8];
        f32x4 acc[2] = {};
#pragma unroll
        for(int ks=0;ks<4;ks++){
#pragma unroll
            for(int jj=0;jj<2;jj++){
                short8 bf = (st & 1) ? wB[jj][ks] : wA[jj][ks];
                acc[jj] = __builtin_amdgcn_mfma_f32_16x16x32_bf16(af[ks], bf, acc[jj], 0, 0, 0);
            }
        }
#pragma unroll
        for(int jj=0;jj<2;jj++){
            float bv = bb[st*128 + (wave*2+jj)*16 + lm];
#pragma unroll
            for(int r=0;r<4;r++) acc[jj][r] += bv;
        }
        if(st==1 || st==3){
#pragma unroll
            for(int jj=0;jj<2;jj++){
#pragma unroll
                for(int r=0;r<4;r++) acc[jj][r] += tsv[jj][r];
                tsv[jj] = acc[jj];
            }
        }
#pragma unroll
        for(int jj=0;jj<2;jj++) cur[jj] = acc[jj];
    }
#pragma unroll
    for(int jj=0;jj<2;jj++)
#pragma unroll
        for(int r=0;r<4;r++)
            tb[(size_t)(r0 + quad*4 + r)*HID_DIM + (wave*2+jj)*16 + lm] = f2bf(cur[jj][r]);
}

// ----------------------- fused Wo gemm + trans spline ----------------------
// 128x48 tiles on f*24+j layout. P 128x51 f32 = 26KB LDS. (256,4). 1
// spline/thread.
__global__ __launch_bounds__(256, 4)
void wo_spline(const ushort_t* __restrict__ tb,
               const ushort_t* __restrict__ Wo2,
               const float* __restrict__ bo2,
               const float* __restrict__ z2oddT,
               ushort_t* __restrict__ zOddT,
               float* __restrict__ ldpart){
    __shared__ __align__(16) char smem[128*51*4];
    __shared__ float ldred[128];
    ushort_t (*As)[72] = (ushort_t(*)[72])smem;                 // 128x64 bf16
    ushort_t (*Bs)[72] = (ushort_t(*)[72])(smem + 128*72*2);    // 48x64 bf16
    float (*P)[51] = (float(*)[51])smem;                        // 128x51 f32
    int tid = threadIdx.x;
    int flat = blockIdx.y*WO_GX + blockIdx.x;
    int flat2 = (flat & 7)*(WO_GX*32/8) + (flat >> 3);          // 4416 = 8*552
    int cbl = flat2 % WO_GX;          // 0..137
    int rbl = flat2 / WO_GX;          // 0..31
    int row0 = rbl*128, col0 = cbl*48;
    int wave = tid>>6, lane = tid&63;
    int lm = lane&15, quad = lane>>4;
    f32x4 acc[2][3] = {};
    for(int k0=0; k0<HID_DIM; k0+=64){
#pragma unroll
        for(int it=0; it<4; it++){
            int c = tid + it*256;
            int r = c>>3, c8 = (c&7)*8;
            *(ushort8*)&As[r][c8] = *(const ushort8*)(tb + (size_t)(row0+r)*HID_DIM + k0 + c8);
        }
#pragma unroll
        for(int it=0; it<2; it++){
            int v = tid + it*256;
            if(v < 384){
                int n = v>>3, c8 = (v&7)*8;
                *(ushort8*)&Bs[n][c8] = *(const ushort8*)(Wo2 + (size_t)(col0+n)*HID_DIM + k0 + c8);
            }
        }
        __syncthreads();
#pragma unroll
        for(int ks=0; ks<2; ks++){
            short8 af[2], bfr[3];
#pragma unroll
            for(int i=0;i<2;i++)
                af[i]  = *(const short8*)&As[wave*32 + i*16 + lm][ks*32 + quad*8];
#pragma unroll
            for(int j=0;j<3;j++)
                bfr[j] = *(const short8*)&Bs[j*16 + lm][ks*32 + quad*8];
#pragma unroll
            for(int i=0;i<2;i++)
#pragma unroll
                for(int j=0;j<3;j++)
                    acc[i][j] = __builtin_amdgcn_mfma_f32_16x16x32_bf16(af[i], bfr[j], acc[i][j], 0, 0, 0);
        }
        __syncthreads();
    }
#pragma unroll
    for(int j=0;j<3;j++){
        int cl = j*16 + lm;
        float bv = bo2[col0 + cl];
#pragma unroll
        for(int i=0;i<2;i++){
            int rl = wave*32 + i*16 + quad*4;
#pragma unroll
            for(int r=0;r<4;r++) P[rl+r][cl] = acc[i][j][r] + bv;
        }
    }
    __syncthreads();
    // One spline per thread: row = tid&127, feat = tid>>7.
    int row = tid & 127, feat = tid >> 7;
    int fg = cbl*2 + feat;
    float ldsum = 0.f;
    const float dend = MIND_C + softplusf(DCONST_C);
    if(fg < F_DIM){
        const float* q = &P[row][feat*24];
        float xv = z2oddT[(size_t)fg*B_ROWS + row0 + row];
        bool inside = (xv >= -TB_C) && (xv <= TB_C);
        float xi = fminf(fmaxf(xv, -TB_C), TB_C);
        // height knots (softmax over q[8..15]) -> bin index
        float eh[8];
        float mh = -1e30f, sh = 0.f;
#pragma unroll
        for(int k=0;k<8;k++){ float u = q[8+k]*RSQRT_HID; eh[k]=u; mh=fmaxf(mh,u); }
#pragma unroll
        for(int k=0;k<8;k++){ eh[k] = __expf(eh[k]-mh); sh += eh[k]; }
        float invh = (1.f - MINB_C*8.f)/sh;
        int idx = 0;
        {
            float cum = 0.f;
#pragma unroll
            for(int k=0;k<7;k++){
                cum += MINB_C + eh[k]*invh;
                float ck = 2.f*TB_C*cum - TB_C;
                idx += (xi >= ck) ? 1 : 0;
            }
        }
        float ich = -TB_C, ihh = 0.f;
        {
            float cum = 0.f, cprev = -TB_C;
#pragma unroll
            for(int k=0;k<8;k++){
                cum += MINB_C + eh[k]*invh;
                float ck = (k==7) ? TB_C : (2.f*TB_C*cum - TB_C);
                if(idx==k){ ich = cprev; ihh = ck - cprev; }
                cprev = ck;
            }
        }
        // width knots
        float ew[8];
        float mw = -1e30f, sw = 0.f;
#pragma unroll
        for(int k=0;k<8;k++){ float u = q[k]*RSQRT_HID; ew[k]=u; mw=fmaxf(mw,u); }
#pragma unroll
        for(int k=0;k<8;k++){ ew[k] = __expf(ew[k]-mw); sw += ew[k]; }
        float invw = (1.f - MINB_C*8.f)/sw;
        float icw = -TB_C, iww = 0.f;
        {
            float cum = 0.f, cprev = -TB_C;
#pragma unroll
            for(int k=0;k<8;k++){
                cum += MINB_C + ew[k]*invw;
                float ck = (k==7) ? TB_C : (2.f*TB_C*cum - TB_C);
                if(idx==k){ icw = cprev; iww = ck - cprev; }
                cprev = ck;
            }
        }
        float d0 = (idx==0) ? dend : (MIND_C + softplusf(q[15+idx]));
        float d1 = (idx==7) ? dend : (MIND_C + softplusf(q[16+idx]));
        float delta = ihh/iww;
        float t  = xi - ich;
        float s  = d0 + d1 - 2.f*delta;
        float a  = t*s + ihh*(delta - d0);
        float b  = ihh*d0 - t*s;
        float c  = -delta*t;
        float disc = fmaxf(b*b - 4.f*a*c, 0.f);
        float root = 2.f*c / (-b - sqrtf(disc));
        float o  = root*iww + icw;
        float tm = root*(1.f-root);
        float den  = delta + s*tm;
        float dnum = delta*delta*(d1*root*root + 2.f*delta*tm + d0*(1.f-root)*(1.f-root));
        float l = 2.f*__logf(den) - __logf(dnum);
        zOddT[(size_t)fg*B_ROWS + row0 + row] = f2bf(inside ? o : xv);
        ldsum = inside ? l : 0.f;
    }
    if(tid >= 128) ldred[tid-128] = ldsum;
    __syncthreads();
    if(tid < 128) ldpart[(size_t)cbl*B_ROWS + row0 + tid] = ldsum + ldred[tid];
}

// --------------------- interleave even/odd z into znb ----------------------
__global__ __launch_bounds__(256)
void interleave_z(const ushort_t* __restrict__ identb,
                  const ushort_t* __restrict__ zOddT,
                  const float* __restrict__ ldpart,
                  ushort_t* __restrict__ znb,
                  float* __restrict__ lq){
    __shared__ ushort_t s[FP_HALF][34];
    int r0 = blockIdx.x*32;
    int tid = threadIdx.x;
#pragma unroll
    for(int i=0;i<36;i++){
        int idx = tid + i*256;
        int f = idx>>5, r = idx&31;
        s[f][r] = zOddT[(size_t)f*B_ROWS + r0 + r];
    }
    __syncthreads();
    int wv = tid>>6, lane = tid&63;
#pragma unroll
    for(int k=0;k<8;k++){
        int r = wv + k*4;
        const ushort_t* idr = identb + (size_t)(r0+r)*F_PAD;
        unsigned* orow = (unsigned*)(znb + (size_t)(r0+r)*D_PAD);
#pragma unroll
        for(int c=0;c<5;c++){
            int f = lane + c*64;
            if(f < FP_HALF){
                unsigned lo = idr[f];
                unsigned hi = s[f][r];
                orow[f] = lo | (hi<<16);
            }
        }
    }
    if(tid < 32){
        float acc = 0.f;
        for(int cb=0; cb<WO_GX; cb++)
            acc += ldpart[(size_t)cb*B_ROWS + r0 + tid];
        lq[r0 + tid] += acc;
    }
}

// --------------------------- spline kernels --------------------------------

__global__ __launch_bounds__(320)
void ident_spline_kernel(const float* __restrict__ z2e, const float* __restrict__ kTb,
                         int layer, ushort_t* __restrict__ identb,
                         float* __restrict__ lq){
    int row = blockIdx.x; int tid = threadIdx.x;
    float ldv = 0.f;
    if(tid < F_DIM){
        const float* kT = kTb + (size_t)layer*F_DIM + tid;
        float cw[9], w[8], ch[9], h[8], d[9];
#pragma unroll
        for(int k=0;k<9;k++) cw[k] = kT[(size_t)k*KT_G];
#pragma unroll
        for(int k=0;k<8;k++) w[k]  = kT[(size_t)(9+k)*KT_G];
#pragma unroll
        for(int k=0;k<9;k++) ch[k] = kT[(size_t)(17+k)*KT_G];
#pragma unroll
        for(int k=0;k<8;k++) h[k]  = kT[(size_t)(26+k)*KT_G];
#pragma unroll
        for(int k=0;k<9;k++) d[k]  = kT[(size_t)(34+k)*KT_G];
        float x = z2e[(size_t)row*FE_PAD + tid];
        float o, l;
        rqs_inv(x, cw, w, ch, h, d, o, l);
        identb[(size_t)row*F_PAD + tid] = f2bf(o);
        ldv = l;
    } else {
        identb[(size_t)row*F_PAD + tid] = 0;
    }
    __shared__ float sm[5];
    float v = ldv;
#pragma unroll
    for(int o=32;o>0;o>>=1) v += __shfl_down(v, o);
    if((tid&63)==0) sm[tid>>6]=v;
    __syncthreads();
    if(tid==0) lq[row] += sm[0]+sm[1]+sm[2]+sm[3]+sm[4];
}

__global__ __launch_bounds__(320)
void finalize_kernel(const ushort_t* __restrict__ zb, const float* __restrict__ loc,
                     const float* __restrict__ lsc, const float* __restrict__ lq,
                     const float* __restrict__ logdiag, float* __restrict__ out){
    int row = blockIdx.x; int tid = threadIdx.x;
    float s = 0.f;
    for(int k=tid; k<D_DIM; k+=320){
        float l = lsc[k];
        float diff = (bf2f(zb[(size_t)row*D_PAD+k])-loc[k])*__expf(-l);
        s += l + 0.5f*diff*diff;
    }
    __shared__ float sm[5];
#pragma unroll
    for(int o=32;o>0;o>>=1) s += __shfl_down(s, o);
    if((tid&63)==0) sm[tid>>6]=s;
    __syncthreads();
    if(tid==0){
        float tot = sm[0]+sm[1]+sm[2]+sm[3]+sm[4];
        out[row] = lq[row] + logdiag[0] - 275.f*1.8378770664f - tot;
    }
}

// ---------------------------------------------------------------------------

extern "C" void kernel_launch(void* const* d_in, const int* in_sizes, int n_in,
                              void* d_out, int out_size, void* d_ws, size_t ws_size,
                              hipStream_t stream){
    const float* x        = (const float*)d_in[0];
    const float* loc      = (const float*)d_in[1];
    const float* lsc      = (const float*)d_in[2];
    const float* Wi       = (const float*)d_in[3];
    const float* bi       = (const float*)d_in[4];
    const float* Wb       = (const float*)d_in[5];
    const float* bb       = (const float*)d_in[6];
    const float* Wo       = (const float*)d_in[7];
    const float* bo       = (const float*)d_in[8];
    const float* uw_u     = (const float*)d_in[9];
    const float* uh_u     = (const float*)d_in[10];
    const float* ud_u     = (const float*)d_in[11];
    const float* lu_lower = (const float*)d_in[12];
    const float* lu_upper = (const float*)d_in[13];
    const float* lu_ud    = (const float*)d_in[14];
    const float* lu_b     = (const float*)d_in[15];
    const int*   perms    = (const int*)d_in[16];
    float* out = (float*)d_out;

    char* base = (char*)d_ws;
    size_t off = 0;
    auto alloc = [&](size_t bytes)->char*{
        char* p = base + off;
        off += (bytes + 255) & ~(size_t)255;
        return p;
    };
    float* lq      = (float*)alloc(B_ROWS*4);
    float* zbias   = (float*)alloc(D_PAD*4);
    float* logdiag = (float*)alloc(64*4);
    float* knots   = (float*)alloc((size_t)43*KT_G*4);
    float* z2e     = (float*)alloc((size_t)B_ROWS*FE_PAD*4);
    float* z2oddT  = (float*)alloc((size_t)FP_HALF*B_ROWS*4);
    float* ldpart  = (float*)alloc((size_t)WO_GX*B_ROWS*4);
    float* bo2     = (float*)alloc((size_t)3*WO24_ROWS*4);
    ushort_t* xb   = (ushort_t*)alloc((size_t)B_ROWS*D_PAD*2);
    ushort_t* zbf0 = (ushort_t*)alloc((size_t)B_ROWS*D_PAD*2);
    ushort_t* zbf1 = (ushort_t*)alloc((size_t)B_ROWS*D_PAD*2);
    ushort_t* zOddT= (ushort_t*)alloc((size_t)FP_HALF*B_ROWS*2);
    ushort_t* Lmb  = (ushort_t*)alloc((size_t)3*N_PAD_A*D_PAD*2);
    ushort_t* UpTb = (ushort_t*)alloc((size_t)3*N_PAD_A*D_PAD*2);
    ushort_t* Apb  = (ushort_t*)alloc((size_t)3*N_PAD_A*D_PAD*2);
    ushort_t* identb=(ushort_t*)alloc((size_t)B_ROWS*F_PAD*2);
    ushort_t* tb   = (ushort_t*)alloc((size_t)B_ROWS*HID_DIM*2);
    ushort_t* WiT  = (ushort_t*)alloc((size_t)3*HID_DIM*F_PAD*2);
    ushort_t* WbT  = (ushort_t*)alloc((size_t)3*4*HID_DIM*HID_DIM*2);
    ushort_t* Wo2  = (ushort_t*)alloc((size_t)3*WO24_ROWS*HID_DIM*2);

    hipMemsetAsync(lq, 0, B_ROWS*sizeof(float), stream);
    hipMemsetAsync(zbias, 0, D_PAD*sizeof(float), stream);
    hipMemsetAsync(zOddT, 0, (size_t)FP_HALF*B_ROWS*2, stream);
    hipMemsetAsync(Wo2, 0, (size_t)3*WO24_ROWS*HID_DIM*2, stream);
    hipMemsetAsync(bo2, 0, (size_t)3*WO24_ROWS*4, stream);
    build_knots_kernel<<<dim3((KT_G+255)/256), dim3(256), 0, stream>>>(uw_u, uh_u, ud_u, knots);
    logdiag_kernel<<<dim3(1), dim3(256), 0, stream>>>(lu_ud, logdiag);
    convert_pad<<<dim3((B_ROWS*D_PAD+255)/256), dim3(256), 0, stream>>>(
        x, xb, B_ROWS, D_DIM, B_ROWS, D_PAD);
    build_L_bf16<<<dim3((D_PAD+255)/256, N_PAD_A, 3), dim3(256), 0, stream>>>(
        lu_lower, Lmb, UpTb);
    dim3 tthr(32,8);
    build_UT_bf16<<<dim3(18, 18, 3), tthr, 0, stream>>>(
        lu_upper, lu_ud, perms, UpTb);
    gemm_mfma_bf<<<dim3(5, 5, 3), dim3(256), 0, stream>>>(
        Lmb, UpTb, zbias, Apb, N_PAD_A, D_PAD, D_PAD,
        (long)N_PAD_A*D_PAD, (long)N_PAD_A*D_PAD, (long)N_PAD_A*D_PAD);
    transpose_convert<0><<<dim3(F_PAD/32, HID_DIM/32, 3), tthr, 0, stream>>>(
        Wi, WiT, F_DIM, HID_DIM, F_PAD, HID_DIM, (long)F_DIM*HID_DIM, (long)F_PAD*HID_DIM);
    transpose_convert<0><<<dim3(HID_DIM/32, HID_DIM/32, 12), tthr, 0, stream>>>(
        Wb, WbT, HID_DIM, HID_DIM, HID_DIM, HID_DIM, (long)HID_DIM*HID_DIM, (long)HID_DIM*HID_DIM);
    transpose_convert<1><<<dim3(HID_DIM/32, OUT_PAD/32, 3), tthr, 0, stream>>>(
        Wo, Wo2, HID_DIM, OUT_DIM, HID_DIM, OUT_PAD, (long)HID_DIM*OUT_DIM, (long)WO24_ROWS*HID_DIM);
    reorder_bias<<<dim3((3*OUT_DIM+255)/256), dim3(256), 0, stream>>>(bo, bo2);

    const ushort_t* zcur_b = xb;
    ushort_t* zbf[2] = {zbf0, zbf1};
    int zi = 0;

    for(int it=0; it<3; ++it){
        int i = 2 - it;

        gemm_lu<<<dim3(N_PAD_A/128, B_ROWS/128), dim3(256), 0, stream>>>(
            zcur_b, Apb + (size_t)i*N_PAD_A*D_PAD, lu_b + (size_t)i*D_DIM,
            z2e, z2oddT);

        ident_spline_kernel<<<dim3(B_ROWS), dim3(320), 0, stream>>>(
            z2e, knots, i, identb, lq);

        resnet_fused<<<dim3(B_ROWS/16), dim3(256), 0, stream>>>(
            identb, WiT + (size_t)i*HID_DIM*F_PAD, bi + (size_t)i*HID_DIM,
            WbT + (size_t)i*4*HID_DIM*HID_DIM, bb + (size_t)i*4*HID_DIM, tb);

        wo_spline<<<dim3(WO_GX, B_ROWS/128), dim3(256), 0, stream>>>(
            tb, Wo2 + (size_t)i*WO24_ROWS*HID_DIM, bo2 + (size_t)i*WO24_ROWS,
            z2oddT, zOddT, ldpart);

        interleave_z<<<dim3(B_ROWS/32), dim3(256), 0, stream>>>(
            identb, zOddT, ldpart, zbf[zi], lq);

        zcur_b = zbf[zi];
        zi ^= 1;
    }

    finalize_kernel<<<dim3(B_ROWS), dim3(320), 0, stream>>>(
        zcur_b, loc, lsc, lq, logdiag, out);
}

// Round 11
// 417.754 us; speedup vs baseline: 1.0879x; 1.0879x over previous
//
#include <hip/hip_runtime.h>

// ---------------------------------------------------------------------------
// DensityEstimator: 3-layer neural spline flow inverse log-prob.
// R16 = exact revert to R14 (413.6us, best known). R15's bundle (gemm_lu
//     fusion + compact z2e + transposed knots) regressed to 454.5us with a
//     pathological 135us/107MB-write ident_spline dispatch at 0.8% occupancy;
//     changes were bundled, attribution impossible -> full revert.
// R14 design: R11 + wo_spline on f*24+j Wo layout (6624 cols vs 8832: -25%
//     MFMA/staging work), 128x48 tiles, 1 spline/thread, launch_bounds(256,4)
//     (NOT 6 — R12's (256,6) VGPR cap spilled spline temps, +73us).
// ---------------------------------------------------------------------------

#define D_DIM 550
#define D_PAD 576
#define N_PAD_A 640
#define F_DIM 275
#define F_PAD 320
#define FP_HALF 288            // D_PAD/2
#define HID_DIM 128
#define OUT_DIM 6325
#define OUT_PAD 6400
#define FT_PAD 276
#define WO24_ROWS (FT_PAD*24)  // 6624
#define WO_GX (WO24_ROWS/48)   // 138 col-blocks (48 cols = 2 features)
#define B_ROWS 4096
#define NBINS 8
#define TB_C 3.0f
#define MINB_C 0.001f
#define MIND_C 0.001f
#define DCONST_C 0.53974233f
#define LUEPS_C 0.001f
#define RSQRT_HID 0.08838834764831845f

typedef unsigned short ushort_t;
typedef __attribute__((ext_vector_type(8))) short short8;
typedef __attribute__((ext_vector_type(8))) unsigned short ushort8;
typedef __attribute__((ext_vector_type(4))) float f32x4;

__device__ __forceinline__ ushort_t f2bf(float f){
    union{float f; unsigned u;} v; v.f = f;
    unsigned r = v.u + 0x7fffu + ((v.u>>16)&1u);
    return (ushort_t)(r>>16);
}
__device__ __forceinline__ float bf2f(ushort_t h){
    union{unsigned u; float f;} v; v.u = ((unsigned)h)<<16;
    return v.f;
}
__device__ __forceinline__ float softplusf(float x){
    return fmaxf(x, 0.f) + __logf(1.f + __expf(-fabsf(x)));
}

__device__ __forceinline__ void knots_from_u(const float* u, float* c, float* w){
    float m = u[0];
#pragma unroll
    for(int k=1;k<NBINS;k++) m = fmaxf(m, u[k]);
    float e[NBINS]; float s = 0.f;
#pragma unroll
    for(int k=0;k<NBINS;k++){ e[k] = __expf(u[k]-m); s += e[k]; }
    float inv = 1.f/s;
    float cum = 0.f;
    c[0] = -TB_C;
#pragma unroll
    for(int k=0;k<NBINS;k++){
        float v = MINB_C + (1.f - MINB_C*(float)NBINS)*e[k]*inv;
        cum += v;
        c[k+1] = 2.f*TB_C*cum - TB_C;
    }
    c[NBINS] = TB_C;
#pragma unroll
    for(int k=0;k<NBINS;k++) w[k] = c[k+1]-c[k];
}

__device__ __forceinline__ void rqs_inv(float x,
                                        const float* cw, const float* w,
                                        const float* ch, const float* h,
                                        const float* d,
                                        float& out, float& ld){
    bool inside = (x >= -TB_C) && (x <= TB_C);
    float xi = fminf(fmaxf(x, -TB_C), TB_C);
    int idx = 0;
#pragma unroll
    for(int j=1;j<NBINS;j++) idx += (xi >= ch[j]) ? 1 : 0;
    float icw=cw[0], iw=w[0], ich=ch[0], ih=h[0], d0=d[0], d1=d[1];
#pragma unroll
    for(int j=1;j<NBINS;j++){
        if(idx==j){ icw=cw[j]; iw=w[j]; ich=ch[j]; ih=h[j]; d0=d[j]; d1=d[j+1]; }
    }
    float delta = ih/iw;
    float t  = xi - ich;
    float s  = d0 + d1 - 2.f*delta;
    float a  = t*s + ih*(delta - d0);
    float b  = ih*d0 - t*s;
    float c  = -delta*t;
    float disc = b*b - 4.f*a*c;
    float root = 2.f*c / (-b - sqrtf(fmaxf(disc, 0.f)));
    float o  = root*iw + icw;
    float tm = root*(1.f-root);
    float den  = delta + s*tm;
    float dnum = delta*delta*(d1*root*root + 2.f*delta*tm + d0*(1.f-root)*(1.f-root));
    float l = 2.f*__logf(den) - __logf(dnum);
    out = inside ? o : x;
    ld  = inside ? l : 0.f;
}

// --------------------------- setup kernels ---------------------------------

__global__ void build_knots_kernel(const float* __restrict__ uw_u,
                                   const float* __restrict__ uh_u,
                                   const float* __restrict__ ud_u,
                                   float* __restrict__ knots){
    int g = blockIdx.x*blockDim.x + threadIdx.x;
    if(g >= 3*F_DIM) return;
    float* kb = knots + (size_t)g*43;
    float c[9], w[8];
    knots_from_u(uw_u + (size_t)g*8, c, w);
#pragma unroll
    for(int k=0;k<9;k++) kb[k]=c[k];
#pragma unroll
    for(int k=0;k<8;k++) kb[9+k]=w[k];
    knots_from_u(uh_u + (size_t)g*8, c, w);
#pragma unroll
    for(int k=0;k<9;k++) kb[17+k]=c[k];
#pragma unroll
    for(int k=0;k<8;k++) kb[26+k]=w[k];
    float dend = MIND_C + softplusf(DCONST_C);
    kb[34]=dend; kb[42]=dend;
    const float* ud = ud_u + (size_t)g*7;
#pragma unroll
    for(int k=0;k<7;k++) kb[35+k] = MIND_C + softplusf(ud[k]);
}

__global__ void logdiag_kernel(const float* __restrict__ lu_ud, float* __restrict__ outv){
    int tid = threadIdx.x;
    float s = 0.f;
    for(int k=tid; k<3*D_DIM; k+=256) s += __logf(softplusf(lu_ud[k]) + LUEPS_C);
#pragma unroll
    for(int o=32;o>0;o>>=1) s += __shfl_down(s, o);
    __shared__ float sm[4];
    if((tid&63)==0) sm[tid>>6]=s;
    __syncthreads();
    if(tid==0) outv[0] = sm[0]+sm[1]+sm[2]+sm[3];
}

// L matrix: coalesced writes (k contiguous along threads).
__global__ void build_L_bf16(const float* __restrict__ lower,
                             ushort_t* __restrict__ Lmb){
    int l = blockIdx.z;
    lower += (size_t)l*D_DIM*D_DIM;
    Lmb += (size_t)l*N_PAD_A*D_PAD;
    int k = blockIdx.x*blockDim.x + threadIdx.x;
    int j = blockIdx.y;
    if(k >= D_DIM) return;
    float lv = (j>k) ? lower[(size_t)j*D_DIM+k] : (j==k ? 1.f : 0.f);
    Lmb[(size_t)j*D_PAD+k] = f2bf(lv);
}

// U^T with perm rows: 32x32 LDS transpose -> line-coalesced perm-row writes.
__global__ void build_UT_bf16(const float* __restrict__ upper,
                              const float* __restrict__ ud,
                              const int* __restrict__ perm,
                              ushort_t* __restrict__ UpTb){
    int l = blockIdx.z;
    upper += (size_t)l*D_DIM*D_DIM; ud += (size_t)l*D_DIM; perm += (size_t)l*D_DIM;
    UpTb += (size_t)l*N_PAD_A*D_PAD;
    __shared__ float t[32][33];
    int j0 = blockIdx.x*32, k0 = blockIdx.y*32;
    int tx = threadIdx.x, ty = threadIdx.y;
#pragma unroll
    for(int i=0;i<32;i+=8){
        int j = j0+ty+i, k = k0+tx;
        float uv = 0.f;
        if(j<D_DIM && k<D_DIM){
            if(j<k)       uv = upper[(size_t)j*D_DIM+k];
            else if(j==k) uv = softplusf(ud[k]) + LUEPS_C;
        }
        t[ty+i][tx] = uv;
    }
    __syncthreads();
#pragma unroll
    for(int i=0;i<32;i+=8){
        int k = k0+ty+i, j = j0+tx;
        if(k<D_DIM)
            UpTb[(size_t)perm[k]*D_PAD + j] = f2bf(t[tx][ty+i]);
    }
}

__global__ void convert_pad(const float* __restrict__ in, ushort_t* __restrict__ out,
                            int M, int K, int Mpad, int Kpad){
    int idx = blockIdx.x*256 + threadIdx.x;
    if(idx >= Mpad*Kpad) return;
    int r = idx / Kpad, c = idx - r*Kpad;
    float v = (r<M && c<K) ? in[(size_t)r*K+c] : 0.f;
    out[idx] = f2bf(v);
}

template<int REMAP>
__global__ void transpose_convert(const float* __restrict__ in, ushort_t* __restrict__ out,
                                  int K, int N, int Kpad, int Npad, long s_in, long s_out){
    in += (size_t)blockIdx.z*s_in; out += (size_t)blockIdx.z*s_out;
    __shared__ float t[32][33];
    int kb = blockIdx.x*32, nb = blockIdx.y*32;
    int tx = threadIdx.x, ty = threadIdx.y;
#pragma unroll
    for(int i=0;i<32;i+=8){
        int k = kb+ty+i, n = nb+tx;
        t[ty+i][tx] = (k<K && n<N) ? in[(size_t)k*N+n] : 0.f;
    }
    __syncthreads();
#pragma unroll
    for(int i=0;i<32;i+=8){
        int n = nb+ty+i, k = kb+tx;
        if(REMAP){
            if(n < OUT_DIM && k < Kpad){
                int f = n/23, j = n - 23*f;
                out[(size_t)(f*24+j)*Kpad+k] = f2bf(t[tx][ty+i]);
            }
        } else if(n<Npad && k<Kpad){
            out[(size_t)n*Kpad+k] = f2bf(t[tx][ty+i]);
        }
    }
}

__global__ void reorder_bias(const float* __restrict__ bo, float* __restrict__ bo2){
    int idx = blockIdx.x*256 + threadIdx.x;
    if(idx >= 3*OUT_DIM) return;
    int l = idx/OUT_DIM, n = idx%OUT_DIM;
    int f = n/23, j = n - 23*f;
    bo2[(size_t)l*WO24_ROWS + f*24 + j] = bo[idx];
}

// ------------------------------ bf16 MFMA gemm -----------------------------
template<int OUTBF>
__global__ __launch_bounds__(256)
void gemm_mfma(const ushort_t* __restrict__ A, const ushort_t* __restrict__ Bt,
               const float* __restrict__ bias, void* __restrict__ Cv,
               int M, int N, int Kpad, long sA, long sB, long sC){
    A  += (size_t)blockIdx.z*sA;
    Bt += (size_t)blockIdx.z*sB;
    __shared__ ushort_t As[128][72];
    __shared__ ushort_t Bs[128][72];
    int tid = threadIdx.x;
    int row0 = blockIdx.y*128, col0 = blockIdx.x*128;
    int wave = tid>>6, lane = tid&63;
    int wm = wave&1, wn = wave>>1;
    int lm = lane&15, quad = lane>>4;
    f32x4 acc[4][4] = {};
    for(int k0=0; k0<Kpad; k0+=64){
#pragma unroll
        for(int it=0; it<4; it++){
            int c = tid + it*256;
            int r = c>>3, c8 = (c&7)*8;
            *(ushort8*)&As[r][c8] = *(const ushort8*)(A + (size_t)(row0+r)*Kpad + k0 + c8);
            *(ushort8*)&Bs[r][c8] = *(const ushort8*)(Bt + (size_t)(col0+r)*Kpad + k0 + c8);
        }
        __syncthreads();
#pragma unroll
        for(int ks=0; ks<2; ks++){
            short8 af[4], bfr[4];
#pragma unroll
            for(int i=0;i<4;i++){
                af[i]  = *(const short8*)&As[wm*64 + i*16 + lm][ks*32 + quad*8];
                bfr[i] = *(const short8*)&Bs[wn*64 + i*16 + lm][ks*32 + quad*8];
            }
#pragma unroll
            for(int i=0;i<4;i++)
#pragma unroll
                for(int j=0;j<4;j++)
                    acc[i][j] = __builtin_amdgcn_mfma_f32_16x16x32_bf16(af[i], bfr[j], acc[i][j], 0, 0, 0);
        }
        __syncthreads();
    }
#pragma unroll
    for(int i=0;i<4;i++){
        int rbase = row0 + wm*64 + i*16 + quad*4;
#pragma unroll
        for(int j=0;j<4;j++){
            int gc = col0 + wn*64 + j*16 + lm;
            if(gc >= N) continue;
            float bv = bias[gc];
#pragma unroll
            for(int r=0;r<4;r++){
                int gr = rbase + r;
                float v = acc[i][j][r] + bv;
                if(OUTBF) ((ushort_t*)Cv + (size_t)blockIdx.z*sC)[(size_t)gr*N+gc] = f2bf(v);
                else      ((float*)Cv + (size_t)blockIdx.z*sC)[(size_t)gr*N+gc] = v;
            }
        }
    }
}

// ------------------------------ fused resnet -------------------------------
// 16 rows/block, grid 256. No LDS weight staging (L2->reg, prefetched).
__global__ __launch_bounds__(256)
void resnet_fused(const ushort_t* __restrict__ identb,
                  const ushort_t* __restrict__ WiT,
                  const float* __restrict__ bi,
                  const ushort_t* __restrict__ WbT,
                  const float* __restrict__ bb,
                  ushort_t* __restrict__ tb){
    __shared__ ushort_t As2[16][136];
    int tid = threadIdx.x, wave = tid>>6, lane = tid&63;
    int lm = lane&15, quad = lane>>4;
    int r0 = blockIdx.x*16;
    int arow = r0 + lm;
    f32x4 cur[2] = {};
    f32x4 tsv[2];
    for(int k0=0; k0<F_PAD; k0+=64){
        const ushort_t* ap = identb + (size_t)arow*F_PAD + k0 + quad*8;
        short8 af0 = *(const short8*)(ap);
        short8 af1 = *(const short8*)(ap + 32);
#pragma unroll
        for(int jj=0;jj<2;jj++){
            int n = (wave*2+jj)*16 + lm;
            const ushort_t* wp = WiT + (size_t)n*F_PAD + k0 + quad*8;
            short8 b0 = *(const short8*)(wp);
            short8 b1 = *(const short8*)(wp + 32);
            cur[jj] = __builtin_amdgcn_mfma_f32_16x16x32_bf16(af0, b0, cur[jj], 0, 0, 0);
            cur[jj] = __builtin_amdgcn_mfma_f32_16x16x32_bf16(af1, b1, cur[jj], 0, 0, 0);
        }
    }
#pragma unroll
    for(int jj=0;jj<2;jj++){
        float bv = bi[(wave*2+jj)*16 + lm];
#pragma unroll
        for(int r=0;r<4;r++) cur[jj][r] += bv;
        tsv[jj] = cur[jj];
    }
    short8 wA[2][4], wB[2][4];
#pragma unroll
    for(int jj=0;jj<2;jj++){
        int n = (wave*2+jj)*16 + lm;
        const ushort_t* wp = WbT + (size_t)n*128 + quad*8;
#pragma unroll
        for(int ks=0;ks<4;ks++) wA[jj][ks] = *(const short8*)(wp + ks*32);
    }
#pragma unroll
    for(int st=0; st<4; st++){
        __syncthreads();
#pragma unroll
        for(int jj=0;jj<2;jj++)
#pragma unroll
            for(int r=0;r<4;r++)
                As2[quad*4 + r][(wave*2+jj)*16 + lm] = f2bf(fmaxf(cur[jj][r], 0.f));
        if(st < 3){
#pragma unroll
            for(int jj=0;jj<2;jj++){
                int n = (wave*2+jj)*16 + lm;
                const ushort_t* wp = WbT + (size_t)(st+1)*128*128 + (size_t)n*128 + quad*8;
#pragma unroll
                for(int ks=0;ks<4;ks++){
                    if(st & 1) wA[jj][ks] = *(const short8*)(wp + ks*32);
                    else       wB[jj][ks] = *(const short8*)(wp + ks*32);
                }
            }
        }
        __syncthreads();
        short8 af[4];
#pragma unroll
        for(int ks=0;ks<4;ks++) af[ks] = *(const short8*)&As2[lm][ks*32 + quad*8];
        f32x4 acc[2] = {};
#pragma unroll
        for(int ks=0;ks<4;ks++){
#pragma unroll
            for(int jj=0;jj<2;jj++){
                short8 bf = (st & 1) ? wB[jj][ks] : wA[jj][ks];
                acc[jj] = __builtin_amdgcn_mfma_f32_16x16x32_bf16(af[ks], bf, acc[jj], 0, 0, 0);
            }
        }
#pragma unroll
        for(int jj=0;jj<2;jj++){
            float bv = bb[st*128 + (wave*2+jj)*16 + lm];
#pragma unroll
            for(int r=0;r<4;r++) acc[jj][r] += bv;
        }
        if(st==1 || st==3){
#pragma unroll
            for(int jj=0;jj<2;jj++){
#pragma unroll
                for(int r=0;r<4;r++) acc[jj][r] += tsv[jj][r];
                tsv[jj] = acc[jj];
            }
        }
#pragma unroll
        for(int jj=0;jj<2;jj++) cur[jj] = acc[jj];
    }
#pragma unroll
    for(int jj=0;jj<2;jj++)
#pragma unroll
        for(int r=0;r<4;r++)
            tb[(size_t)(r0 + quad*4 + r)*HID_DIM + (wave*2+jj)*16 + lm] = f2bf(cur[jj][r]);
}

// ------------------- z2 odd-column transpose (compact) ---------------------
__global__ __launch_bounds__(256)
void zodd_transpose(const float* __restrict__ z2, float* __restrict__ z2oddT){
    __shared__ float s[32][65];
    int r0 = blockIdx.x*64, f0 = blockIdx.y*32;
    int tid = threadIdx.x;
    int f = tid & 31, rb = tid >> 5;
#pragma unroll
    for(int rr=0; rr<8; rr++){
        int r = rb + rr*8;
        int fg = f0 + f;
        float v = (fg < F_DIM) ? z2[(size_t)(r0+r)*D_DIM + 2*fg + 1] : 0.f;
        s[f][r] = v;
    }
    __syncthreads();
    int lane = tid & 63, fb = tid >> 6;
#pragma unroll
    for(int ff=0; ff<8; ff++){
        int fo = fb + ff*4;
        z2oddT[(size_t)(f0+fo)*B_ROWS + r0 + lane] = s[fo][lane];
    }
}

// ----------------------- fused Wo gemm + trans spline ----------------------
// 128x48 tiles on f*24+j layout. P 128x51 f32 = 26KB LDS. (256,4). 1
// spline/thread. Bs staging: 384 chunks via 2-iteration guarded loop.
__global__ __launch_bounds__(256, 4)
void wo_spline(const ushort_t* __restrict__ tb,
               const ushort_t* __restrict__ Wo2,
               const float* __restrict__ bo2,
               const float* __restrict__ z2oddT,
               ushort_t* __restrict__ zOddT,
               float* __restrict__ ldpart){
    __shared__ __align__(16) char smem[128*51*4];
    __shared__ float ldred[128];
    ushort_t (*As)[72] = (ushort_t(*)[72])smem;                 // 128x64 bf16
    ushort_t (*Bs)[72] = (ushort_t(*)[72])(smem + 128*72*2);    // 48x64 bf16
    float (*P)[51] = (float(*)[51])smem;                        // 128x51 f32
    int tid = threadIdx.x;
    int flat = blockIdx.y*WO_GX + blockIdx.x;
    int flat2 = (flat & 7)*(WO_GX*32/8) + (flat >> 3);          // 4416 = 8*552
    int cbl = flat2 % WO_GX;          // 0..137
    int rbl = flat2 / WO_GX;          // 0..31
    int row0 = rbl*128, col0 = cbl*48;
    int wave = tid>>6, lane = tid&63;
    int lm = lane&15, quad = lane>>4;
    f32x4 acc[2][3] = {};
    for(int k0=0; k0<HID_DIM; k0+=64){
#pragma unroll
        for(int it=0; it<4; it++){
            int c = tid + it*256;
            int r = c>>3, c8 = (c&7)*8;
            *(ushort8*)&As[r][c8] = *(const ushort8*)(tb + (size_t)(row0+r)*HID_DIM + k0 + c8);
        }
#pragma unroll
        for(int it=0; it<2; it++){
            int v = tid + it*256;
            if(v < 384){
                int n = v>>3, c8 = (v&7)*8;
                *(ushort8*)&Bs[n][c8] = *(const ushort8*)(Wo2 + (size_t)(col0+n)*HID_DIM + k0 + c8);
            }
        }
        __syncthreads();
#pragma unroll
        for(int ks=0; ks<2; ks++){
            short8 af[2], bfr[3];
#pragma unroll
            for(int i=0;i<2;i++)
                af[i]  = *(const short8*)&As[wave*32 + i*16 + lm][ks*32 + quad*8];
#pragma unroll
            for(int j=0;j<3;j++)
                bfr[j] = *(const short8*)&Bs[j*16 + lm][ks*32 + quad*8];
#pragma unroll
            for(int i=0;i<2;i++)
#pragma unroll
                for(int j=0;j<3;j++)
                    acc[i][j] = __builtin_amdgcn_mfma_f32_16x16x32_bf16(af[i], bfr[j], acc[i][j], 0, 0, 0);
        }
        __syncthreads();
    }
#pragma unroll
    for(int j=0;j<3;j++){
        int cl = j*16 + lm;
        float bv = bo2[col0 + cl];
#pragma unroll
        for(int i=0;i<2;i++){
            int rl = wave*32 + i*16 + quad*4;
#pragma unroll
            for(int r=0;r<4;r++) P[rl+r][cl] = acc[i][j][r] + bv;
        }
    }
    __syncthreads();
    // One spline per thread: row = tid&127, feat = tid>>7.
    int row = tid & 127, feat = tid >> 7;
    int fg = cbl*2 + feat;
    float ldsum = 0.f;
    const float dend = MIND_C + softplusf(DCONST_C);
    if(fg < F_DIM){
        const float* q = &P[row][feat*24];
        float xv = z2oddT[(size_t)fg*B_ROWS + row0 + row];
        bool inside = (xv >= -TB_C) && (xv <= TB_C);
        float xi = fminf(fmaxf(xv, -TB_C), TB_C);
        // height knots (softmax over q[8..15]) -> bin index
        float eh[8];
        float mh = -1e30f, sh = 0.f;
#pragma unroll
        for(int k=0;k<8;k++){ float u = q[8+k]*RSQRT_HID; eh[k]=u; mh=fmaxf(mh,u); }
#pragma unroll
        for(int k=0;k<8;k++){ eh[k] = __expf(eh[k]-mh); sh += eh[k]; }
        float invh = (1.f - MINB_C*8.f)/sh;
        int idx = 0;
        {
            float cum = 0.f;
#pragma unroll
            for(int k=0;k<7;k++){
                cum += MINB_C + eh[k]*invh;
                float ck = 2.f*TB_C*cum - TB_C;
                idx += (xi >= ck) ? 1 : 0;
            }
        }
        float ich = -TB_C, ihh = 0.f;
        {
            float cum = 0.f, cprev = -TB_C;
#pragma unroll
            for(int k=0;k<8;k++){
                cum += MINB_C + eh[k]*invh;
                float ck = (k==7) ? TB_C : (2.f*TB_C*cum - TB_C);
                if(idx==k){ ich = cprev; ihh = ck - cprev; }
                cprev = ck;
            }
        }
        // width knots
        float ew[8];
        float mw = -1e30f, sw = 0.f;
#pragma unroll
        for(int k=0;k<8;k++){ float u = q[k]*RSQRT_HID; ew[k]=u; mw=fmaxf(mw,u); }
#pragma unroll
        for(int k=0;k<8;k++){ ew[k] = __expf(ew[k]-mw); sw += ew[k]; }
        float invw = (1.f - MINB_C*8.f)/sw;
        float icw = -TB_C, iww = 0.f;
        {
            float cum = 0.f, cprev = -TB_C;
#pragma unroll
            for(int k=0;k<8;k++){
                cum += MINB_C + ew[k]*invw;
                float ck = (k==7) ? TB_C : (2.f*TB_C*cum - TB_C);
                if(idx==k){ icw = cprev; iww = ck - cprev; }
                cprev = ck;
            }
        }
        float d0 = (idx==0) ? dend : (MIND_C + softplusf(q[15+idx]));
        float d1 = (idx==7) ? dend : (MIND_C + softplusf(q[16+idx]));
        float delta = ihh/iww;
        float t  = xi - ich;
        float s  = d0 + d1 - 2.f*delta;
        float a  = t*s + ihh*(delta - d0);
        float b  = ihh*d0 - t*s;
        float c  = -delta*t;
        float disc = fmaxf(b*b - 4.f*a*c, 0.f);
        float root = 2.f*c / (-b - sqrtf(disc));
        float o  = root*iww + icw;
        float tm = root*(1.f-root);
        float den  = delta + s*tm;
        float dnum = delta*delta*(d1*root*root + 2.f*delta*tm + d0*(1.f-root)*(1.f-root));
        float l = 2.f*__logf(den) - __logf(dnum);
        zOddT[(size_t)fg*B_ROWS + row0 + row] = f2bf(inside ? o : xv);
        ldsum = inside ? l : 0.f;
    }
    if(tid >= 128) ldred[tid-128] = ldsum;
    __syncthreads();
    if(tid < 128) ldpart[(size_t)cbl*B_ROWS + row0 + tid] = ldsum + ldred[tid];
}

// --------------------- interleave even/odd z into znb ----------------------
__global__ __launch_bounds__(256)
void interleave_z(const ushort_t* __restrict__ identb,
                  const ushort_t* __restrict__ zOddT,
                  const float* __restrict__ ldpart,
                  ushort_t* __restrict__ znb,
                  float* __restrict__ lq){
    __shared__ ushort_t s[FP_HALF][34];
    int r0 = blockIdx.x*32;
    int tid = threadIdx.x;
#pragma unroll
    for(int i=0;i<36;i++){
        int idx = tid + i*256;
        int f = idx>>5, r = idx&31;
        s[f][r] = zOddT[(size_t)f*B_ROWS + r0 + r];
    }
    __syncthreads();
    int wv = tid>>6, lane = tid&63;
#pragma unroll
    for(int k=0;k<8;k++){
        int r = wv + k*4;
        const ushort_t* idr = identb + (size_t)(r0+r)*F_PAD;
        unsigned* orow = (unsigned*)(znb + (size_t)(r0+r)*D_PAD);
#pragma unroll
        for(int c=0;c<5;c++){
            int f = lane + c*64;
            if(f < FP_HALF){
                unsigned lo = idr[f];
                unsigned hi = s[f][r];
                orow[f] = lo | (hi<<16);
            }
        }
    }
    if(tid < 32){
        float acc = 0.f;
        for(int cb=0; cb<WO_GX; cb++)
            acc += ldpart[(size_t)cb*B_ROWS + r0 + tid];
        lq[r0 + tid] += acc;
    }
}

// --------------------------- spline kernels --------------------------------

__global__ __launch_bounds__(320)
void ident_spline_kernel(const float* __restrict__ z2, const float* __restrict__ knots,
                         int layer, ushort_t* __restrict__ identb,
                         float* __restrict__ lq){
    int row = blockIdx.x; int tid = threadIdx.x;
    float ldv = 0.f;
    if(tid < F_DIM){
        const float* kb = knots + ((size_t)(layer*F_DIM + tid))*43;
        float x = z2[(size_t)row*D_DIM + 2*tid];
        float o, l;
        rqs_inv(x, kb, kb+9, kb+17, kb+26, kb+34, o, l);
        identb[(size_t)row*F_PAD + tid] = f2bf(o);
        ldv = l;
    } else {
        identb[(size_t)row*F_PAD + tid] = 0;
    }
    __shared__ float sm[5];
    float v = ldv;
#pragma unroll
    for(int o=32;o>0;o>>=1) v += __shfl_down(v, o);
    if((tid&63)==0) sm[tid>>6]=v;
    __syncthreads();
    if(tid==0) lq[row] += sm[0]+sm[1]+sm[2]+sm[3]+sm[4];
}

__global__ __launch_bounds__(320)
void finalize_kernel(const ushort_t* __restrict__ zb, const float* __restrict__ loc,
                     const float* __restrict__ lsc, const float* __restrict__ lq,
                     const float* __restrict__ logdiag, float* __restrict__ out){
    int row = blockIdx.x; int tid = threadIdx.x;
    float s = 0.f;
    for(int k=tid; k<D_DIM; k+=320){
        float l = lsc[k];
        float diff = (bf2f(zb[(size_t)row*D_PAD+k])-loc[k])*__expf(-l);
        s += l + 0.5f*diff*diff;
    }
    __shared__ float sm[5];
#pragma unroll
    for(int o=32;o>0;o>>=1) s += __shfl_down(s, o);
    if((tid&63)==0) sm[tid>>6]=s;
    __syncthreads();
    if(tid==0){
        float tot = sm[0]+sm[1]+sm[2]+sm[3]+sm[4];
        out[row] = lq[row] + logdiag[0] - 275.f*1.8378770664f - tot;
    }
}

// ---------------------------------------------------------------------------

extern "C" void kernel_launch(void* const* d_in, const int* in_sizes, int n_in,
                              void* d_out, int out_size, void* d_ws, size_t ws_size,
                              hipStream_t stream){
    const float* x        = (const float*)d_in[0];
    const float* loc      = (const float*)d_in[1];
    const float* lsc      = (const float*)d_in[2];
    const float* Wi       = (const float*)d_in[3];
    const float* bi       = (const float*)d_in[4];
    const float* Wb       = (const float*)d_in[5];
    const float* bb       = (const float*)d_in[6];
    const float* Wo       = (const float*)d_in[7];
    const float* bo       = (const float*)d_in[8];
    const float* uw_u     = (const float*)d_in[9];
    const float* uh_u     = (const float*)d_in[10];
    const float* ud_u     = (const float*)d_in[11];
    const float* lu_lower = (const float*)d_in[12];
    const float* lu_upper = (const float*)d_in[13];
    const float* lu_ud    = (const float*)d_in[14];
    const float* lu_b     = (const float*)d_in[15];
    const int*   perms    = (const int*)d_in[16];
    float* out = (float*)d_out;

    char* base = (char*)d_ws;
    size_t off = 0;
    auto alloc = [&](size_t bytes)->char*{
        char* p = base + off;
        off += (bytes + 255) & ~(size_t)255;
        return p;
    };
    float* lq      = (float*)alloc(B_ROWS*4);
    float* zbias   = (float*)alloc(D_PAD*4);
    float* logdiag = (float*)alloc(64*4);
    float* knots   = (float*)alloc((size_t)3*F_DIM*43*4);
    float* z2      = (float*)alloc((size_t)B_ROWS*D_DIM*4);
    float* z2oddT  = (float*)alloc((size_t)FP_HALF*B_ROWS*4);
    float* ldpart  = (float*)alloc((size_t)WO_GX*B_ROWS*4);
    float* bo2     = (float*)alloc((size_t)3*WO24_ROWS*4);
    ushort_t* xb   = (ushort_t*)alloc((size_t)B_ROWS*D_PAD*2);
    ushort_t* zbf0 = (ushort_t*)alloc((size_t)B_ROWS*D_PAD*2);
    ushort_t* zbf1 = (ushort_t*)alloc((size_t)B_ROWS*D_PAD*2);
    ushort_t* zOddT= (ushort_t*)alloc((size_t)FP_HALF*B_ROWS*2);
    ushort_t* Lmb  = (ushort_t*)alloc((size_t)3*N_PAD_A*D_PAD*2);
    ushort_t* UpTb = (ushort_t*)alloc((size_t)3*N_PAD_A*D_PAD*2);
    ushort_t* Apb  = (ushort_t*)alloc((size_t)3*N_PAD_A*D_PAD*2);
    ushort_t* identb=(ushort_t*)alloc((size_t)B_ROWS*F_PAD*2);
    ushort_t* tb   = (ushort_t*)alloc((size_t)B_ROWS*HID_DIM*2);
    ushort_t* WiT  = (ushort_t*)alloc((size_t)3*HID_DIM*F_PAD*2);
    ushort_t* WbT  = (ushort_t*)alloc((size_t)3*4*HID_DIM*HID_DIM*2);
    ushort_t* Wo2  = (ushort_t*)alloc((size_t)3*WO24_ROWS*HID_DIM*2);

    hipMemsetAsync(lq, 0, B_ROWS*sizeof(float), stream);
    hipMemsetAsync(zbias, 0, D_PAD*sizeof(float), stream);
    hipMemsetAsync(zOddT, 0, (size_t)FP_HALF*B_ROWS*2, stream);
    hipMemsetAsync(Lmb, 0, (size_t)3*N_PAD_A*D_PAD*2, stream);
    hipMemsetAsync(UpTb, 0, (size_t)3*N_PAD_A*D_PAD*2, stream);
    hipMemsetAsync(Wo2, 0, (size_t)3*WO24_ROWS*HID_DIM*2, stream);
    hipMemsetAsync(bo2, 0, (size_t)3*WO24_ROWS*4, stream);
    build_knots_kernel<<<dim3((3*F_DIM+255)/256), dim3(256), 0, stream>>>(uw_u, uh_u, ud_u, knots);
    logdiag_kernel<<<dim3(1), dim3(256), 0, stream>>>(lu_ud, logdiag);
    convert_pad<<<dim3((B_ROWS*D_PAD+255)/256), dim3(256), 0, stream>>>(
        x, xb, B_ROWS, D_DIM, B_ROWS, D_PAD);
    build_L_bf16<<<dim3((D_DIM+255)/256, D_DIM, 3), dim3(256), 0, stream>>>(
        lu_lower, Lmb);
    dim3 tthr(32,8);
    build_UT_bf16<<<dim3(18, 18, 3), tthr, 0, stream>>>(
        lu_upper, lu_ud, perms, UpTb);
    gemm_mfma<1><<<dim3(5, 5, 3), dim3(256), 0, stream>>>(
        Lmb, UpTb, zbias, Apb, N_PAD_A, D_PAD, D_PAD,
        (long)N_PAD_A*D_PAD, (long)N_PAD_A*D_PAD, (long)N_PAD_A*D_PAD);
    transpose_convert<0><<<dim3(F_PAD/32, HID_DIM/32, 3), tthr, 0, stream>>>(
        Wi, WiT, F_DIM, HID_DIM, F_PAD, HID_DIM, (long)F_DIM*HID_DIM, (long)F_PAD*HID_DIM);
    transpose_convert<0><<<dim3(HID_DIM/32, HID_DIM/32, 12), tthr, 0, stream>>>(
        Wb, WbT, HID_DIM, HID_DIM, HID_DIM, HID_DIM, (long)HID_DIM*HID_DIM, (long)HID_DIM*HID_DIM);
    transpose_convert<1><<<dim3(HID_DIM/32, OUT_PAD/32, 3), tthr, 0, stream>>>(
        Wo, Wo2, HID_DIM, OUT_DIM, HID_DIM, OUT_PAD, (long)HID_DIM*OUT_DIM, (long)WO24_ROWS*HID_DIM);
    reorder_bias<<<dim3((3*OUT_DIM+255)/256), dim3(256), 0, stream>>>(bo, bo2);

    const ushort_t* zcur_b = xb;
    ushort_t* zbf[2] = {zbf0, zbf1};
    int zi = 0;

    for(int it=0; it<3; ++it){
        int i = 2 - it;

        gemm_mfma<0><<<dim3(N_PAD_A/128, B_ROWS/128), dim3(256), 0, stream>>>(
            zcur_b, Apb + (size_t)i*N_PAD_A*D_PAD, lu_b + (size_t)i*D_DIM,
            z2, B_ROWS, D_DIM, D_PAD, 0, 0, 0);

        zodd_transpose<<<dim3(B_ROWS/64, FP_HALF/32), dim3(256), 0, stream>>>(
            z2, z2oddT);

        ident_spline_kernel<<<dim3(B_ROWS), dim3(320), 0, stream>>>(
            z2, knots, i, identb, lq);

        resnet_fused<<<dim3(B_ROWS/16), dim3(256), 0, stream>>>(
            identb, WiT + (size_t)i*HID_DIM*F_PAD, bi + (size_t)i*HID_DIM,
            WbT + (size_t)i*4*HID_DIM*HID_DIM, bb + (size_t)i*4*HID_DIM, tb);

        wo_spline<<<dim3(WO_GX, B_ROWS/128), dim3(256), 0, stream>>>(
            tb, Wo2 + (size_t)i*WO24_ROWS*HID_DIM, bo2 + (size_t)i*WO24_ROWS,
            z2oddT, zOddT, ldpart);

        interleave_z<<<dim3(B_ROWS/32), dim3(256), 0, stream>>>(
            identb, zOddT, ldpart, zbf[zi], lq);

        zcur_b = zbf[zi];
        zi ^= 1;
    }

    finalize_kernel<<<dim3(B_ROWS), dim3(320), 0, stream>>>(
        zcur_b, loc, lsc, lq, logdiag, out);
}

// Round 12
// 372.488 us; speedup vs baseline: 1.2201x; 1.1215x over previous
//
#include <hip/hip_runtime.h>

// ---------------------------------------------------------------------------
// DensityEstimator: 3-layer neural spline flow inverse log-prob.
// R17 (from R16 = 417.8us ~= R14 413.6 best): dispatch-node reduction,
//     35 -> 21 graph nodes. Kernel BODIES byte-identical to R16; only
//     blockIdx decode changed (transcription-bug discipline).
//  (1) fat_setup: knots+logdiag+reorder_bias+convert_pad+build_L+
//      zero{lq,zbias,zOddT pad rows,Wo2 pad rows,bo2 pad} in ONE dispatch
//      (replaces 5 memsets + 5 kernels; pad-zero index sets disjoint from
//      real writes).
//  (2) fat_trans: 3x transpose_convert + build_UT job-decoded (one dispatch).
//  (3) zident: zodd_transpose (blocks 0..575, tid<256-guarded, uniform
//      syncs) + ident_spline (blocks 576..4671) per layer (replaces 2).
//  Lmb/UpTb memsets kept (ordering-sensitive). wo_spline/resnet/gemm
//  unchanged. Theory: ~4-5us/node overhead -> predict ~355-375us; if ~413,
//  node overhead ~1us -> practical floor.
// ---------------------------------------------------------------------------

#define D_DIM 550
#define D_PAD 576
#define N_PAD_A 640
#define F_DIM 275
#define F_PAD 320
#define FP_HALF 288            // D_PAD/2
#define HID_DIM 128
#define OUT_DIM 6325
#define OUT_PAD 6400
#define FT_PAD 276
#define WO24_ROWS (FT_PAD*24)  // 6624
#define WO_GX (WO24_ROWS/48)   // 138 col-blocks (48 cols = 2 features)
#define B_ROWS 4096
#define NBINS 8
#define TB_C 3.0f
#define MINB_C 0.001f
#define MIND_C 0.001f
#define DCONST_C 0.53974233f
#define LUEPS_C 0.001f
#define RSQRT_HID 0.08838834764831845f

typedef unsigned short ushort_t;
typedef __attribute__((ext_vector_type(8))) short short8;
typedef __attribute__((ext_vector_type(8))) unsigned short ushort8;
typedef __attribute__((ext_vector_type(4))) float f32x4;

__device__ __forceinline__ ushort_t f2bf(float f){
    union{float f; unsigned u;} v; v.f = f;
    unsigned r = v.u + 0x7fffu + ((v.u>>16)&1u);
    return (ushort_t)(r>>16);
}
__device__ __forceinline__ float bf2f(ushort_t h){
    union{unsigned u; float f;} v; v.u = ((unsigned)h)<<16;
    return v.f;
}
__device__ __forceinline__ float softplusf(float x){
    return fmaxf(x, 0.f) + __logf(1.f + __expf(-fabsf(x)));
}

__device__ __forceinline__ void knots_from_u(const float* u, float* c, float* w){
    float m = u[0];
#pragma unroll
    for(int k=1;k<NBINS;k++) m = fmaxf(m, u[k]);
    float e[NBINS]; float s = 0.f;
#pragma unroll
    for(int k=0;k<NBINS;k++){ e[k] = __expf(u[k]-m); s += e[k]; }
    float inv = 1.f/s;
    float cum = 0.f;
    c[0] = -TB_C;
#pragma unroll
    for(int k=0;k<NBINS;k++){
        float v = MINB_C + (1.f - MINB_C*(float)NBINS)*e[k]*inv;
        cum += v;
        c[k+1] = 2.f*TB_C*cum - TB_C;
    }
    c[NBINS] = TB_C;
#pragma unroll
    for(int k=0;k<NBINS;k++) w[k] = c[k+1]-c[k];
}

__device__ __forceinline__ void rqs_inv(float x,
                                        const float* cw, const float* w,
                                        const float* ch, const float* h,
                                        const float* d,
                                        float& out, float& ld){
    bool inside = (x >= -TB_C) && (x <= TB_C);
    float xi = fminf(fmaxf(x, -TB_C), TB_C);
    int idx = 0;
#pragma unroll
    for(int j=1;j<NBINS;j++) idx += (xi >= ch[j]) ? 1 : 0;
    float icw=cw[0], iw=w[0], ich=ch[0], ih=h[0], d0=d[0], d1=d[1];
#pragma unroll
    for(int j=1;j<NBINS;j++){
        if(idx==j){ icw=cw[j]; iw=w[j]; ich=ch[j]; ih=h[j]; d0=d[j]; d1=d[j+1]; }
    }
    float delta = ih/iw;
    float t  = xi - ich;
    float s  = d0 + d1 - 2.f*delta;
    float a  = t*s + ih*(delta - d0);
    float b  = ih*d0 - t*s;
    float c  = -delta*t;
    float disc = b*b - 4.f*a*c;
    float root = 2.f*c / (-b - sqrtf(fmaxf(disc, 0.f)));
    float o  = root*iw + icw;
    float tm = root*(1.f-root);
    float den  = delta + s*tm;
    float dnum = delta*delta*(d1*root*root + 2.f*delta*tm + d0*(1.f-root)*(1.f-root));
    float l = 2.f*__logf(den) - __logf(dnum);
    out = inside ? o : x;
    ld  = inside ? l : 0.f;
}

// --------------------------- fat setup kernel ------------------------------
// Job ranges (256-thread blocks):
//  [0,4)        build_knots        g = b*256+tid, g<825
//  [4,5)        logdiag
//  [5,80)       reorder_bias       idx = (b-5)*256+tid < 18975
//  [80,9296)    convert_pad        idx = (b-80)*256+tid < 4096*576
//  [9296,14246) build_L            lb = b-9296 over (3 xblk, 550 j, 3 layer)
//  [14246,14262) zero lq           p < 4096
//  [14262,14265) zero zbias        p < 576
//  [14265,14369) zero zOddT rows 275..287 (u32 view, p < 13*2048)
//  [14369,14594) zero Wo2 pad rows (u32 view, p < 57408)
//  [14594,14598) zero bo2 pad      p < 897
__global__ __launch_bounds__(256)
void fat_setup(const float* __restrict__ uw_u, const float* __restrict__ uh_u,
               const float* __restrict__ ud_u, float* __restrict__ knots,
               const float* __restrict__ lu_ud, float* __restrict__ logdiag,
               const float* __restrict__ bo, float* __restrict__ bo2,
               const float* __restrict__ x, ushort_t* __restrict__ xb,
               const float* __restrict__ lower, ushort_t* __restrict__ Lmb,
               float* __restrict__ lq, float* __restrict__ zbias,
               ushort_t* __restrict__ zOddT, ushort_t* __restrict__ Wo2){
    __shared__ float sm[4];
    int b = blockIdx.x, tid = threadIdx.x;
    if(b < 4){
        int g = b*256 + tid;
        if(g >= 3*F_DIM) return;
        float* kb = knots + (size_t)g*43;
        float c[9], w[8];
        knots_from_u(uw_u + (size_t)g*8, c, w);
#pragma unroll
        for(int k=0;k<9;k++) kb[k]=c[k];
#pragma unroll
        for(int k=0;k<8;k++) kb[9+k]=w[k];
        knots_from_u(uh_u + (size_t)g*8, c, w);
#pragma unroll
        for(int k=0;k<9;k++) kb[17+k]=c[k];
#pragma unroll
        for(int k=0;k<8;k++) kb[26+k]=w[k];
        float dend = MIND_C + softplusf(DCONST_C);
        kb[34]=dend; kb[42]=dend;
        const float* ud = ud_u + (size_t)g*7;
#pragma unroll
        for(int k=0;k<7;k++) kb[35+k] = MIND_C + softplusf(ud[k]);
    } else if(b < 5){
        float s = 0.f;
        for(int k=tid; k<3*D_DIM; k+=256) s += __logf(softplusf(lu_ud[k]) + LUEPS_C);
#pragma unroll
        for(int o=32;o>0;o>>=1) s += __shfl_down(s, o);
        if((tid&63)==0) sm[tid>>6]=s;
        __syncthreads();
        if(tid==0) logdiag[0] = sm[0]+sm[1]+sm[2]+sm[3];
    } else if(b < 80){
        int idx = (b-5)*256 + tid;
        if(idx >= 3*OUT_DIM) return;
        int l = idx/OUT_DIM, n = idx%OUT_DIM;
        int f = n/23, j = n - 23*f;
        bo2[(size_t)l*WO24_ROWS + f*24 + j] = bo[idx];
    } else if(b < 9296){
        int idx = (b-80)*256 + tid;
        if(idx >= B_ROWS*D_PAD) return;
        int r = idx / D_PAD, c = idx - r*D_PAD;
        float v = (r<B_ROWS && c<D_DIM) ? x[(size_t)r*D_DIM+c] : 0.f;
        xb[idx] = f2bf(v);
    } else if(b < 14246){
        int lb = b - 9296;
        int l = lb/1650;
        int rem = lb - l*1650;
        int j = rem/3;
        int xb3 = rem - j*3;
        int k = xb3*256 + tid;
        if(k >= D_DIM) return;
        const float* lw = lower + (size_t)l*D_DIM*D_DIM;
        ushort_t* Lp = Lmb + (size_t)l*N_PAD_A*D_PAD;
        float lv = (j>k) ? lw[(size_t)j*D_DIM+k] : (j==k ? 1.f : 0.f);
        Lp[(size_t)j*D_PAD+k] = f2bf(lv);
    } else if(b < 14262){
        int p = (b-14246)*256 + tid;
        if(p < B_ROWS) lq[p] = 0.f;
    } else if(b < 14265){
        int p = (b-14262)*256 + tid;
        if(p < D_PAD) zbias[p] = 0.f;
    } else if(b < 14369){
        int p = (b-14265)*256 + tid;
        if(p < 13*2048){
            int row = 275 + p/2048, ci = p%2048;
            ((unsigned*)zOddT)[(size_t)row*2048 + ci] = 0u;
        }
    } else if(b < 14594){
        int p = (b-14369)*256 + tid;
        if(p < 57408){
            int l = p/19136, r2 = p%19136;
            int rl = r2/64, ci = r2%64;
            int row = (rl<275) ? rl*24+23 : 6600+(rl-275);
            ((unsigned*)Wo2)[((size_t)l*WO24_ROWS + row)*64 + ci] = 0u;
        }
    } else {
        int p = (b-14594)*256 + tid;
        if(p < 897){
            int l = p/299, r = p%299;
            int idx2 = (r<275) ? r*24+23 : 6600+(r-275);
            bo2[(size_t)l*WO24_ROWS + idx2] = 0.f;
        }
    }
}

// --------------------------- fat transpose kernel --------------------------
// 256 threads, tx=tid&31, ty=tid>>5 (32x8 shape). Jobs:
//  [0,120)      Wi -> WiT     (remap 0) grids (10,4,3)
//  [120,312)    Wb -> WbT     (remap 0) grids (4,4,12)
//  [312,2712)   Wo -> Wo2     (remap 1) grids (4,200,3)
//  [2712,3684)  build_UT      grids (18,18,3)
__device__ __forceinline__ void tc_body(const float* in, ushort_t* out,
                                        int K, int N, int Kpad, int Npad,
                                        long s_in, long s_out, int remap,
                                        int bx, int by, int bz,
                                        int tx, int ty, float (*t)[33]){
    in += (size_t)bz*s_in; out += (size_t)bz*s_out;
    int kb = bx*32, nb = by*32;
#pragma unroll
    for(int i=0;i<32;i+=8){
        int k = kb+ty+i, n = nb+tx;
        t[ty+i][tx] = (k<K && n<N) ? in[(size_t)k*N+n] : 0.f;
    }
    __syncthreads();
#pragma unroll
    for(int i=0;i<32;i+=8){
        int n = nb+ty+i, k = kb+tx;
        if(remap){
            if(n < OUT_DIM && k < Kpad){
                int f = n/23, j = n - 23*f;
                out[(size_t)(f*24+j)*Kpad+k] = f2bf(t[tx][ty+i]);
            }
        } else if(n<Npad && k<Kpad){
            out[(size_t)n*Kpad+k] = f2bf(t[tx][ty+i]);
        }
    }
}

__global__ __launch_bounds__(256)
void fat_trans(const float* __restrict__ Wi, ushort_t* __restrict__ WiT,
               const float* __restrict__ Wb, ushort_t* __restrict__ WbT,
               const float* __restrict__ Wo, ushort_t* __restrict__ Wo2,
               const float* __restrict__ upper, const float* __restrict__ ud,
               const int* __restrict__ perm, ushort_t* __restrict__ UpTb){
    __shared__ float t[32][33];
    int b = blockIdx.x, tid = threadIdx.x;
    int tx = tid & 31, ty = tid >> 5;
    if(b < 120){
        int z = b/40, rem = b%40, by = rem/10, bx = rem%10;
        tc_body(Wi, WiT, F_DIM, HID_DIM, F_PAD, HID_DIM,
                (long)F_DIM*HID_DIM, (long)F_PAD*HID_DIM, 0, bx, by, z, tx, ty, t);
    } else if(b < 312){
        int lb = b-120;
        int z = lb/16, rem = lb%16, by = rem/4, bx = rem%4;
        tc_body(Wb, WbT, HID_DIM, HID_DIM, HID_DIM, HID_DIM,
                (long)HID_DIM*HID_DIM, (long)HID_DIM*HID_DIM, 0, bx, by, z, tx, ty, t);
    } else if(b < 2712){
        int lb = b-312;
        int z = lb/800, rem = lb%800, by = rem/4, bx = rem%4;
        tc_body(Wo, Wo2, HID_DIM, OUT_DIM, HID_DIM, OUT_PAD,
                (long)HID_DIM*OUT_DIM, (long)WO24_ROWS*HID_DIM, 1, bx, by, z, tx, ty, t);
    } else {
        int lb = b-2712;
        int l = lb/324, rem = lb%324, by = rem/18, bx = rem%18;
        const float* up = upper + (size_t)l*D_DIM*D_DIM;
        const float* udl = ud + (size_t)l*D_DIM;
        const int* pm = perm + (size_t)l*D_DIM;
        ushort_t* Up = UpTb + (size_t)l*N_PAD_A*D_PAD;
        int j0 = bx*32, k0 = by*32;
#pragma unroll
        for(int i=0;i<32;i+=8){
            int j = j0+ty+i, k = k0+tx;
            float uv = 0.f;
            if(j<D_DIM && k<D_DIM){
                if(j<k)       uv = up[(size_t)j*D_DIM+k];
                else if(j==k) uv = softplusf(udl[k]) + LUEPS_C;
            }
            t[ty+i][tx] = uv;
        }
        __syncthreads();
#pragma unroll
        for(int i=0;i<32;i+=8){
            int k = k0+ty+i, j = j0+tx;
            if(k<D_DIM)
                Up[(size_t)pm[k]*D_PAD + j] = f2bf(t[tx][ty+i]);
        }
    }
}

// ------------------------------ bf16 MFMA gemm -----------------------------
template<int OUTBF>
__global__ __launch_bounds__(256)
void gemm_mfma(const ushort_t* __restrict__ A, const ushort_t* __restrict__ Bt,
               const float* __restrict__ bias, void* __restrict__ Cv,
               int M, int N, int Kpad, long sA, long sB, long sC){
    A  += (size_t)blockIdx.z*sA;
    Bt += (size_t)blockIdx.z*sB;
    __shared__ ushort_t As[128][72];
    __shared__ ushort_t Bs[128][72];
    int tid = threadIdx.x;
    int row0 = blockIdx.y*128, col0 = blockIdx.x*128;
    int wave = tid>>6, lane = tid&63;
    int wm = wave&1, wn = wave>>1;
    int lm = lane&15, quad = lane>>4;
    f32x4 acc[4][4] = {};
    for(int k0=0; k0<Kpad; k0+=64){
#pragma unroll
        for(int it=0; it<4; it++){
            int c = tid + it*256;
            int r = c>>3, c8 = (c&7)*8;
            *(ushort8*)&As[r][c8] = *(const ushort8*)(A + (size_t)(row0+r)*Kpad + k0 + c8);
            *(ushort8*)&Bs[r][c8] = *(const ushort8*)(Bt + (size_t)(col0+r)*Kpad + k0 + c8);
        }
        __syncthreads();
#pragma unroll
        for(int ks=0; ks<2; ks++){
            short8 af[4], bfr[4];
#pragma unroll
            for(int i=0;i<4;i++){
                af[i]  = *(const short8*)&As[wm*64 + i*16 + lm][ks*32 + quad*8];
                bfr[i] = *(const short8*)&Bs[wn*64 + i*16 + lm][ks*32 + quad*8];
            }
#pragma unroll
            for(int i=0;i<4;i++)
#pragma unroll
                for(int j=0;j<4;j++)
                    acc[i][j] = __builtin_amdgcn_mfma_f32_16x16x32_bf16(af[i], bfr[j], acc[i][j], 0, 0, 0);
        }
        __syncthreads();
    }
#pragma unroll
    for(int i=0;i<4;i++){
        int rbase = row0 + wm*64 + i*16 + quad*4;
#pragma unroll
        for(int j=0;j<4;j++){
            int gc = col0 + wn*64 + j*16 + lm;
            if(gc >= N) continue;
            float bv = bias[gc];
#pragma unroll
            for(int r=0;r<4;r++){
                int gr = rbase + r;
                float v = acc[i][j][r] + bv;
                if(OUTBF) ((ushort_t*)Cv + (size_t)blockIdx.z*sC)[(size_t)gr*N+gc] = f2bf(v);
                else      ((float*)Cv + (size_t)blockIdx.z*sC)[(size_t)gr*N+gc] = v;
            }
        }
    }
}

// ------------------------------ fused resnet -------------------------------
// 16 rows/block, grid 256. No LDS weight staging (L2->reg, prefetched).
__global__ __launch_bounds__(256)
void resnet_fused(const ushort_t* __restrict__ identb,
                  const ushort_t* __restrict__ WiT,
                  const float* __restrict__ bi,
                  const ushort_t* __restrict__ WbT,
                  const float* __restrict__ bb,
                  ushort_t* __restrict__ tb){
    __shared__ ushort_t As2[16][136];
    int tid = threadIdx.x, wave = tid>>6, lane = tid&63;
    int lm = lane&15, quad = lane>>4;
    int r0 = blockIdx.x*16;
    int arow = r0 + lm;
    f32x4 cur[2] = {};
    f32x4 tsv[2];
    for(int k0=0; k0<F_PAD; k0+=64){
        const ushort_t* ap = identb + (size_t)arow*F_PAD + k0 + quad*8;
        short8 af0 = *(const short8*)(ap);
        short8 af1 = *(const short8*)(ap + 32);
#pragma unroll
        for(int jj=0;jj<2;jj++){
            int n = (wave*2+jj)*16 + lm;
            const ushort_t* wp = WiT + (size_t)n*F_PAD + k0 + quad*8;
            short8 b0 = *(const short8*)(wp);
            short8 b1 = *(const short8*)(wp + 32);
            cur[jj] = __builtin_amdgcn_mfma_f32_16x16x32_bf16(af0, b0, cur[jj], 0, 0, 0);
            cur[jj] = __builtin_amdgcn_mfma_f32_16x16x32_bf16(af1, b1, cur[jj], 0, 0, 0);
        }
    }
#pragma unroll
    for(int jj=0;jj<2;jj++){
        float bv = bi[(wave*2+jj)*16 + lm];
#pragma unroll
        for(int r=0;r<4;r++) cur[jj][r] += bv;
        tsv[jj] = cur[jj];
    }
    short8 wA[2][4], wB[2][4];
#pragma unroll
    for(int jj=0;jj<2;jj++){
        int n = (wave*2+jj)*16 + lm;
        const ushort_t* wp = WbT + (size_t)n*128 + quad*8;
#pragma unroll
        for(int ks=0;ks<4;ks++) wA[jj][ks] = *(const short8*)(wp + ks*32);
    }
#pragma unroll
    for(int st=0; st<4; st++){
        __syncthreads();
#pragma unroll
        for(int jj=0;jj<2;jj++)
#pragma unroll
            for(int r=0;r<4;r++)
                As2[quad*4 + r][(wave*2+jj)*16 + lm] = f2bf(fmaxf(cur[jj][r], 0.f));
        if(st < 3){
#pragma unroll
            for(int jj=0;jj<2;jj++){
                int n = (wave*2+jj)*16 + lm;
                const ushort_t* wp = WbT + (size_t)(st+1)*128*128 + (size_t)n*128 + quad*8;
#pragma unroll
                for(int ks=0;ks<4;ks++){
                    if(st & 1) wA[jj][ks] = *(const short8*)(wp + ks*32);
                    else       wB[jj][ks] = *(const short8*)(wp + ks*32);
                }
            }
        }
        __syncthreads();
        short8 af[4];
#pragma unroll
        for(int ks=0;ks<4;ks++) af[ks] = *(const short8*)&As2[lm][ks*32 + quad*8];
        f32x4 acc[2] = {};
#pragma unroll
        for(int ks=0;ks<4;ks++){
#pragma unroll
            for(int jj=0;jj<2;jj++){
                short8 bf = (st & 1) ? wB[jj][ks] : wA[jj][ks];
                acc[jj] = __builtin_amdgcn_mfma_f32_16x16x32_bf16(af[ks], bf, acc[jj], 0, 0, 0);
            }
        }
#pragma unroll
        for(int jj=0;jj<2;jj++){
            float bv = bb[st*128 + (wave*2+jj)*16 + lm];
#pragma unroll
            for(int r=0;r<4;r++) acc[jj][r] += bv;
        }
        if(st==1 || st==3){
#pragma unroll
            for(int jj=0;jj<2;jj++){
#pragma unroll
                for(int r=0;r<4;r++) acc[jj][r] += tsv[jj][r];
                tsv[jj] = acc[jj];
            }
        }
#pragma unroll
        for(int jj=0;jj<2;jj++) cur[jj] = acc[jj];
    }
#pragma unroll
    for(int jj=0;jj<2;jj++)
#pragma unroll
        for(int r=0;r<4;r++)
            tb[(size_t)(r0 + quad*4 + r)*HID_DIM + (wave*2+jj)*16 + lm] = f2bf(cur[jj][r]);
}

// ------------- fat zident: zodd_transpose + ident_spline -------------------
// 320 threads. Blocks [0,576): zodd (tid<256 active; decode b%64 -> r0,
// b/64 -> f0). Blocks [576, 4672): ident_spline with row = b-576.
__global__ __launch_bounds__(320)
void zident(const float* __restrict__ z2, const float* __restrict__ knots,
            int layer, float* __restrict__ z2oddT,
            ushort_t* __restrict__ identb, float* __restrict__ lq){
    __shared__ float s[32][65];
    __shared__ float sm[5];
    int b = blockIdx.x, tid = threadIdx.x;
    if(b < 576){
        int r0 = (b & 63)*64, f0 = (b >> 6)*32;
        int f = tid & 31, rb = tid >> 5;
        if(tid < 256){
#pragma unroll
            for(int rr=0; rr<8; rr++){
                int r = rb + rr*8;
                int fg = f0 + f;
                float v = (fg < F_DIM) ? z2[(size_t)(r0+r)*D_DIM + 2*fg + 1] : 0.f;
                s[f][r] = v;
            }
        }
        __syncthreads();
        if(tid < 256){
            int lane = tid & 63, fb = tid >> 6;
#pragma unroll
            for(int ff=0; ff<8; ff++){
                int fo = fb + ff*4;
                z2oddT[(size_t)(f0+fo)*B_ROWS + r0 + lane] = s[fo][lane];
            }
        }
    } else {
        int row = b - 576;
        float ldv = 0.f;
        if(tid < F_DIM){
            const float* kb = knots + ((size_t)(layer*F_DIM + tid))*43;
            float x = z2[(size_t)row*D_DIM + 2*tid];
            float o, l;
            rqs_inv(x, kb, kb+9, kb+17, kb+26, kb+34, o, l);
            identb[(size_t)row*F_PAD + tid] = f2bf(o);
            ldv = l;
        } else {
            identb[(size_t)row*F_PAD + tid] = 0;
        }
        float v = ldv;
#pragma unroll
        for(int o=32;o>0;o>>=1) v += __shfl_down(v, o);
        if((tid&63)==0) sm[tid>>6]=v;
        __syncthreads();
        if(tid==0) lq[row] += sm[0]+sm[1]+sm[2]+sm[3]+sm[4];
    }
}

// ----------------------- fused Wo gemm + trans spline ----------------------
// 128x48 tiles on f*24+j layout. P 128x51 f32 = 26KB LDS. (256,4). 1
// spline/thread. Bs staging: 384 chunks via 2-iteration guarded loop.
__global__ __launch_bounds__(256, 4)
void wo_spline(const ushort_t* __restrict__ tb,
               const ushort_t* __restrict__ Wo2,
               const float* __restrict__ bo2,
               const float* __restrict__ z2oddT,
               ushort_t* __restrict__ zOddT,
               float* __restrict__ ldpart){
    __shared__ __align__(16) char smem[128*51*4];
    __shared__ float ldred[128];
    ushort_t (*As)[72] = (ushort_t(*)[72])smem;                 // 128x64 bf16
    ushort_t (*Bs)[72] = (ushort_t(*)[72])(smem + 128*72*2);    // 48x64 bf16
    float (*P)[51] = (float(*)[51])smem;                        // 128x51 f32
    int tid = threadIdx.x;
    int flat = blockIdx.y*WO_GX + blockIdx.x;
    int flat2 = (flat & 7)*(WO_GX*32/8) + (flat >> 3);          // 4416 = 8*552
    int cbl = flat2 % WO_GX;          // 0..137
    int rbl = flat2 / WO_GX;          // 0..31
    int row0 = rbl*128, col0 = cbl*48;
    int wave = tid>>6, lane = tid&63;
    int lm = lane&15, quad = lane>>4;
    f32x4 acc[2][3] = {};
    for(int k0=0; k0<HID_DIM; k0+=64){
#pragma unroll
        for(int it=0; it<4; it++){
            int c = tid + it*256;
            int r = c>>3, c8 = (c&7)*8;
            *(ushort8*)&As[r][c8] = *(const ushort8*)(tb + (size_t)(row0+r)*HID_DIM + k0 + c8);
        }
#pragma unroll
        for(int it=0; it<2; it++){
            int v = tid + it*256;
            if(v < 384){
                int n = v>>3, c8 = (v&7)*8;
                *(ushort8*)&Bs[n][c8] = *(const ushort8*)(Wo2 + (size_t)(col0+n)*HID_DIM + k0 + c8);
            }
        }
        __syncthreads();
#pragma unroll
        for(int ks=0; ks<2; ks++){
            short8 af[2], bfr[3];
#pragma unroll
            for(int i=0;i<2;i++)
                af[i]  = *(const short8*)&As[wave*32 + i*16 + lm][ks*32 + quad*8];
#pragma unroll
            for(int j=0;j<3;j++)
                bfr[j] = *(const short8*)&Bs[j*16 + lm][ks*32 + quad*8];
#pragma unroll
            for(int i=0;i<2;i++)
#pragma unroll
                for(int j=0;j<3;j++)
                    acc[i][j] = __builtin_amdgcn_mfma_f32_16x16x32_bf16(af[i], bfr[j], acc[i][j], 0, 0, 0);
        }
        __syncthreads();
    }
#pragma unroll
    for(int j=0;j<3;j++){
        int cl = j*16 + lm;
        float bv = bo2[col0 + cl];
#pragma unroll
        for(int i=0;i<2;i++){
            int rl = wave*32 + i*16 + quad*4;
#pragma unroll
            for(int r=0;r<4;r++) P[rl+r][cl] = acc[i][j][r] + bv;
        }
    }
    __syncthreads();
    // One spline per thread: row = tid&127, feat = tid>>7.
    int row = tid & 127, feat = tid >> 7;
    int fg = cbl*2 + feat;
    float ldsum = 0.f;
    const float dend = MIND_C + softplusf(DCONST_C);
    if(fg < F_DIM){
        const float* q = &P[row][feat*24];
        float xv = z2oddT[(size_t)fg*B_ROWS + row0 + row];
        bool inside = (xv >= -TB_C) && (xv <= TB_C);
        float xi = fminf(fmaxf(xv, -TB_C), TB_C);
        // height knots (softmax over q[8..15]) -> bin index
        float eh[8];
        float mh = -1e30f, sh = 0.f;
#pragma unroll
        for(int k=0;k<8;k++){ float u = q[8+k]*RSQRT_HID; eh[k]=u; mh=fmaxf(mh,u); }
#pragma unroll
        for(int k=0;k<8;k++){ eh[k] = __expf(eh[k]-mh); sh += eh[k]; }
        float invh = (1.f - MINB_C*8.f)/sh;
        int idx = 0;
        {
            float cum = 0.f;
#pragma unroll
            for(int k=0;k<7;k++){
                cum += MINB_C + eh[k]*invh;
                float ck = 2.f*TB_C*cum - TB_C;
                idx += (xi >= ck) ? 1 : 0;
            }
        }
        float ich = -TB_C, ihh = 0.f;
        {
            float cum = 0.f, cprev = -TB_C;
#pragma unroll
            for(int k=0;k<8;k++){
                cum += MINB_C + eh[k]*invh;
                float ck = (k==7) ? TB_C : (2.f*TB_C*cum - TB_C);
                if(idx==k){ ich = cprev; ihh = ck - cprev; }
                cprev = ck;
            }
        }
        // width knots
        float ew[8];
        float mw = -1e30f, sw = 0.f;
#pragma unroll
        for(int k=0;k<8;k++){ float u = q[k]*RSQRT_HID; ew[k]=u; mw=fmaxf(mw,u); }
#pragma unroll
        for(int k=0;k<8;k++){ ew[k] = __expf(ew[k]-mw); sw += ew[k]; }
        float invw = (1.f - MINB_C*8.f)/sw;
        float icw = -TB_C, iww = 0.f;
        {
            float cum = 0.f, cprev = -TB_C;
#pragma unroll
            for(int k=0;k<8;k++){
                cum += MINB_C + ew[k]*invw;
                float ck = (k==7) ? TB_C : (2.f*TB_C*cum - TB_C);
                if(idx==k){ icw = cprev; iww = ck - cprev; }
                cprev = ck;
            }
        }
        float d0 = (idx==0) ? dend : (MIND_C + softplusf(q[15+idx]));
        float d1 = (idx==7) ? dend : (MIND_C + softplusf(q[16+idx]));
        float delta = ihh/iww;
        float t  = xi - ich;
        float s  = d0 + d1 - 2.f*delta;
        float a  = t*s + ihh*(delta - d0);
        float b  = ihh*d0 - t*s;
        float c  = -delta*t;
        float disc = fmaxf(b*b - 4.f*a*c, 0.f);
        float root = 2.f*c / (-b - sqrtf(disc));
        float o  = root*iww + icw;
        float tm = root*(1.f-root);
        float den  = delta + s*tm;
        float dnum = delta*delta*(d1*root*root + 2.f*delta*tm + d0*(1.f-root)*(1.f-root));
        float l = 2.f*__logf(den) - __logf(dnum);
        zOddT[(size_t)fg*B_ROWS + row0 + row] = f2bf(inside ? o : xv);
        ldsum = inside ? l : 0.f;
    }
    if(tid >= 128) ldred[tid-128] = ldsum;
    __syncthreads();
    if(tid < 128) ldpart[(size_t)cbl*B_ROWS + row0 + tid] = ldsum + ldred[tid];
}

// --------------------- interleave even/odd z into znb ----------------------
__global__ __launch_bounds__(256)
void interleave_z(const ushort_t* __restrict__ identb,
                  const ushort_t* __restrict__ zOddT,
                  const float* __restrict__ ldpart,
                  ushort_t* __restrict__ znb,
                  float* __restrict__ lq){
    __shared__ ushort_t s[FP_HALF][34];
    int r0 = blockIdx.x*32;
    int tid = threadIdx.x;
#pragma unroll
    for(int i=0;i<36;i++){
        int idx = tid + i*256;
        int f = idx>>5, r = idx&31;
        s[f][r] = zOddT[(size_t)f*B_ROWS + r0 + r];
    }
    __syncthreads();
    int wv = tid>>6, lane = tid&63;
#pragma unroll
    for(int k=0;k<8;k++){
        int r = wv + k*4;
        const ushort_t* idr = identb + (size_t)(r0+r)*F_PAD;
        unsigned* orow = (unsigned*)(znb + (size_t)(r0+r)*D_PAD);
#pragma unroll
        for(int c=0;c<5;c++){
            int f = lane + c*64;
            if(f < FP_HALF){
                unsigned lo = idr[f];
                unsigned hi = s[f][r];
                orow[f] = lo | (hi<<16);
            }
        }
    }
    if(tid < 32){
        float acc = 0.f;
        for(int cb=0; cb<WO_GX; cb++)
            acc += ldpart[(size_t)cb*B_ROWS + r0 + tid];
        lq[r0 + tid] += acc;
    }
}

// --------------------------- finalize --------------------------------------

__global__ __launch_bounds__(320)
void finalize_kernel(const ushort_t* __restrict__ zb, const float* __restrict__ loc,
                     const float* __restrict__ lsc, const float* __restrict__ lq,
                     const float* __restrict__ logdiag, float* __restrict__ out){
    int row = blockIdx.x; int tid = threadIdx.x;
    float s = 0.f;
    for(int k=tid; k<D_DIM; k+=320){
        float l = lsc[k];
        float diff = (bf2f(zb[(size_t)row*D_PAD+k])-loc[k])*__expf(-l);
        s += l + 0.5f*diff*diff;
    }
    __shared__ float sm[5];
#pragma unroll
    for(int o=32;o>0;o>>=1) s += __shfl_down(s, o);
    if((tid&63)==0) sm[tid>>6]=s;
    __syncthreads();
    if(tid==0){
        float tot = sm[0]+sm[1]+sm[2]+sm[3]+sm[4];
        out[row] = lq[row] + logdiag[0] - 275.f*1.8378770664f - tot;
    }
}

// ---------------------------------------------------------------------------

extern "C" void kernel_launch(void* const* d_in, const int* in_sizes, int n_in,
                              void* d_out, int out_size, void* d_ws, size_t ws_size,
                              hipStream_t stream){
    const float* x        = (const float*)d_in[0];
    const float* loc      = (const float*)d_in[1];
    const float* lsc      = (const float*)d_in[2];
    const float* Wi       = (const float*)d_in[3];
    const float* bi       = (const float*)d_in[4];
    const float* Wb       = (const float*)d_in[5];
    const float* bb       = (const float*)d_in[6];
    const float* Wo       = (const float*)d_in[7];
    const float* bo       = (const float*)d_in[8];
    const float* uw_u     = (const float*)d_in[9];
    const float* uh_u     = (const float*)d_in[10];
    const float* ud_u     = (const float*)d_in[11];
    const float* lu_lower = (const float*)d_in[12];
    const float* lu_upper = (const float*)d_in[13];
    const float* lu_ud    = (const float*)d_in[14];
    const float* lu_b     = (const float*)d_in[15];
    const int*   perms    = (const int*)d_in[16];
    float* out = (float*)d_out;

    char* base = (char*)d_ws;
    size_t off = 0;
    auto alloc = [&](size_t bytes)->char*{
        char* p = base + off;
        off += (bytes + 255) & ~(size_t)255;
        return p;
    };
    float* lq      = (float*)alloc(B_ROWS*4);
    float* zbias   = (float*)alloc(D_PAD*4);
    float* logdiag = (float*)alloc(64*4);
    float* knots   = (float*)alloc((size_t)3*F_DIM*43*4);
    float* z2      = (float*)alloc((size_t)B_ROWS*D_DIM*4);
    float* z2oddT  = (float*)alloc((size_t)FP_HALF*B_ROWS*4);
    float* ldpart  = (float*)alloc((size_t)WO_GX*B_ROWS*4);
    float* bo2     = (float*)alloc((size_t)3*WO24_ROWS*4);
    ushort_t* xb   = (ushort_t*)alloc((size_t)B_ROWS*D_PAD*2);
    ushort_t* zbf0 = (ushort_t*)alloc((size_t)B_ROWS*D_PAD*2);
    ushort_t* zbf1 = (ushort_t*)alloc((size_t)B_ROWS*D_PAD*2);
    ushort_t* zOddT= (ushort_t*)alloc((size_t)FP_HALF*B_ROWS*2);
    ushort_t* Lmb  = (ushort_t*)alloc((size_t)3*N_PAD_A*D_PAD*2);
    ushort_t* UpTb = (ushort_t*)alloc((size_t)3*N_PAD_A*D_PAD*2);
    ushort_t* Apb  = (ushort_t*)alloc((size_t)3*N_PAD_A*D_PAD*2);
    ushort_t* identb=(ushort_t*)alloc((size_t)B_ROWS*F_PAD*2);
    ushort_t* tb   = (ushort_t*)alloc((size_t)B_ROWS*HID_DIM*2);
    ushort_t* WiT  = (ushort_t*)alloc((size_t)3*HID_DIM*F_PAD*2);
    ushort_t* WbT  = (ushort_t*)alloc((size_t)3*4*HID_DIM*HID_DIM*2);
    ushort_t* Wo2  = (ushort_t*)alloc((size_t)3*WO24_ROWS*HID_DIM*2);

    // Lmb/UpTb pad zeroing kept as memsets (ordering-sensitive vs build_L /
    // build_UT which only write k<550 / perm-rows).
    hipMemsetAsync(Lmb, 0, (size_t)3*N_PAD_A*D_PAD*2, stream);
    hipMemsetAsync(UpTb, 0, (size_t)3*N_PAD_A*D_PAD*2, stream);

    fat_setup<<<dim3(14598), dim3(256), 0, stream>>>(
        uw_u, uh_u, ud_u, knots, lu_ud, logdiag, bo, bo2,
        x, xb, lu_lower, Lmb, lq, zbias, zOddT, Wo2);

    fat_trans<<<dim3(3684), dim3(256), 0, stream>>>(
        Wi, WiT, Wb, WbT, Wo, Wo2, lu_upper, lu_ud, perms, UpTb);

    gemm_mfma<1><<<dim3(5, 5, 3), dim3(256), 0, stream>>>(
        Lmb, UpTb, zbias, Apb, N_PAD_A, D_PAD, D_PAD,
        (long)N_PAD_A*D_PAD, (long)N_PAD_A*D_PAD, (long)N_PAD_A*D_PAD);

    const ushort_t* zcur_b = xb;
    ushort_t* zbf[2] = {zbf0, zbf1};
    int zi = 0;

    for(int it=0; it<3; ++it){
        int i = 2 - it;

        gemm_mfma<0><<<dim3(N_PAD_A/128, B_ROWS/128), dim3(256), 0, stream>>>(
            zcur_b, Apb + (size_t)i*N_PAD_A*D_PAD, lu_b + (size_t)i*D_DIM,
            z2, B_ROWS, D_DIM, D_PAD, 0, 0, 0);

        zident<<<dim3(576 + B_ROWS), dim3(320), 0, stream>>>(
            z2, knots, i, z2oddT, identb, lq);

        resnet_fused<<<dim3(B_ROWS/16), dim3(256), 0, stream>>>(
            identb, WiT + (size_t)i*HID_DIM*F_PAD, bi + (size_t)i*HID_DIM,
            WbT + (size_t)i*4*HID_DIM*HID_DIM, bb + (size_t)i*4*HID_DIM, tb);

        wo_spline<<<dim3(WO_GX, B_ROWS/128), dim3(256), 0, stream>>>(
            tb, Wo2 + (size_t)i*WO24_ROWS*HID_DIM, bo2 + (size_t)i*WO24_ROWS,
            z2oddT, zOddT, ldpart);

        interleave_z<<<dim3(B_ROWS/32), dim3(256), 0, stream>>>(
            identb, zOddT, ldpart, zbf[zi], lq);

        zcur_b = zbf[zi];
        zi ^= 1;
    }

    finalize_kernel<<<dim3(B_ROWS), dim3(320), 0, stream>>>(
        zcur_b, loc, lsc, lq, logdiag, out);
}

// Round 13
// 363.739 us; speedup vs baseline: 1.2495x; 1.0241x over previous
//
#include <hip/hip_runtime.h>

// ---------------------------------------------------------------------------
// DensityEstimator: 3-layer neural spline flow inverse log-prob.
// R18 (from R17 = 372.5us, -45 via node reduction at ~3.2us/node):
//  21 -> 17 graph nodes, same lever:
//  (1) Lmb/UpTb pad-zeroing folded into fat_setup (index sets disjoint from
//      build_L / build_UT writes) -> drop the last 2 memsets.
//  (2) fat_trans merged INTO fat_setup (reads only inputs; writes disjoint
//      from all fat_setup writes) -> one mega setup dispatch.
//  (3) finalize merged into last interleave_z via template<LAST>: block for
//      rows r0..r0+31 already holds all 550 cols (identb + s[] LDS, bf16
//      bit-identical) and computes lq itself; LAST skips znb writes and
//      wave-reduces the Gaussian term per row.
//  gemm/resnet/wo_spline/zident bodies byte-identical to R17.
// ---------------------------------------------------------------------------

#define D_DIM 550
#define D_PAD 576
#define N_PAD_A 640
#define F_DIM 275
#define F_PAD 320
#define FP_HALF 288            // D_PAD/2
#define HID_DIM 128
#define OUT_DIM 6325
#define OUT_PAD 6400
#define FT_PAD 276
#define WO24_ROWS (FT_PAD*24)  // 6624
#define WO_GX (WO24_ROWS/48)   // 138 col-blocks (48 cols = 2 features)
#define B_ROWS 4096
#define NBINS 8
#define TB_C 3.0f
#define MINB_C 0.001f
#define MIND_C 0.001f
#define DCONST_C 0.53974233f
#define LUEPS_C 0.001f
#define RSQRT_HID 0.08838834764831845f
// u32 geometry for Lmb/UpTb pad zeroing
#define LU_U32_PER_LAYER 184320        // 640*576/2
#define PAD_STRIP 7150                 // 550 rows * 13 u32 (cols 550..575)
#define PAD_PER_LAYER 33070            // 7150 + 90*288
#define PAD_TOTAL 99210                // *3 layers
#define PAD_BLOCKS 388

typedef unsigned short ushort_t;
typedef __attribute__((ext_vector_type(8))) short short8;
typedef __attribute__((ext_vector_type(8))) unsigned short ushort8;
typedef __attribute__((ext_vector_type(4))) float f32x4;

__device__ __forceinline__ ushort_t f2bf(float f){
    union{float f; unsigned u;} v; v.f = f;
    unsigned r = v.u + 0x7fffu + ((v.u>>16)&1u);
    return (ushort_t)(r>>16);
}
__device__ __forceinline__ float bf2f(ushort_t h){
    union{unsigned u; float f;} v; v.u = ((unsigned)h)<<16;
    return v.f;
}
__device__ __forceinline__ float softplusf(float x){
    return fmaxf(x, 0.f) + __logf(1.f + __expf(-fabsf(x)));
}

__device__ __forceinline__ void knots_from_u(const float* u, float* c, float* w){
    float m = u[0];
#pragma unroll
    for(int k=1;k<NBINS;k++) m = fmaxf(m, u[k]);
    float e[NBINS]; float s = 0.f;
#pragma unroll
    for(int k=0;k<NBINS;k++){ e[k] = __expf(u[k]-m); s += e[k]; }
    float inv = 1.f/s;
    float cum = 0.f;
    c[0] = -TB_C;
#pragma unroll
    for(int k=0;k<NBINS;k++){
        float v = MINB_C + (1.f - MINB_C*(float)NBINS)*e[k]*inv;
        cum += v;
        c[k+1] = 2.f*TB_C*cum - TB_C;
    }
    c[NBINS] = TB_C;
#pragma unroll
    for(int k=0;k<NBINS;k++) w[k] = c[k+1]-c[k];
}

__device__ __forceinline__ void rqs_inv(float x,
                                        const float* cw, const float* w,
                                        const float* ch, const float* h,
                                        const float* d,
                                        float& out, float& ld){
    bool inside = (x >= -TB_C) && (x <= TB_C);
    float xi = fminf(fmaxf(x, -TB_C), TB_C);
    int idx = 0;
#pragma unroll
    for(int j=1;j<NBINS;j++) idx += (xi >= ch[j]) ? 1 : 0;
    float icw=cw[0], iw=w[0], ich=ch[0], ih=h[0], d0=d[0], d1=d[1];
#pragma unroll
    for(int j=1;j<NBINS;j++){
        if(idx==j){ icw=cw[j]; iw=w[j]; ich=ch[j]; ih=h[j]; d0=d[j]; d1=d[j+1]; }
    }
    float delta = ih/iw;
    float t  = xi - ich;
    float s  = d0 + d1 - 2.f*delta;
    float a  = t*s + ih*(delta - d0);
    float b  = ih*d0 - t*s;
    float c  = -delta*t;
    float disc = b*b - 4.f*a*c;
    float root = 2.f*c / (-b - sqrtf(fmaxf(disc, 0.f)));
    float o  = root*iw + icw;
    float tm = root*(1.f-root);
    float den  = delta + s*tm;
    float dnum = delta*delta*(d1*root*root + 2.f*delta*tm + d0*(1.f-root)*(1.f-root));
    float l = 2.f*__logf(den) - __logf(dnum);
    out = inside ? o : x;
    ld  = inside ? l : 0.f;
}

// ------------------------ transpose helper (32x8) --------------------------
__device__ __forceinline__ void tc_body(const float* in, ushort_t* out,
                                        int K, int N, int Kpad, int Npad,
                                        long s_in, long s_out, int remap,
                                        int bx, int by, int bz,
                                        int tx, int ty, float (*t)[33]){
    in += (size_t)bz*s_in; out += (size_t)bz*s_out;
    int kb = bx*32, nb = by*32;
#pragma unroll
    for(int i=0;i<32;i+=8){
        int k = kb+ty+i, n = nb+tx;
        t[ty+i][tx] = (k<K && n<N) ? in[(size_t)k*N+n] : 0.f;
    }
    __syncthreads();
#pragma unroll
    for(int i=0;i<32;i+=8){
        int n = nb+ty+i, k = kb+tx;
        if(remap){
            if(n < OUT_DIM && k < Kpad){
                int f = n/23, j = n - 23*f;
                out[(size_t)(f*24+j)*Kpad+k] = f2bf(t[tx][ty+i]);
            }
        } else if(n<Npad && k<Kpad){
            out[(size_t)n*Kpad+k] = f2bf(t[tx][ty+i]);
        }
    }
}

// --------------------------- mega setup kernel -----------------------------
// Job ranges (256-thread blocks):
//  [0,4)            build_knots
//  [4,5)            logdiag
//  [5,80)           reorder_bias
//  [80,9296)        convert_pad (x -> xb)
//  [9296,14246)     build_L
//  [14246,14262)    zero lq
//  [14262,14265)    zero zbias
//  [14265,14369)    zero zOddT rows 275..287
//  [14369,14594)    zero Wo2 pad rows
//  [14594,14598)    zero bo2 pad
//  [14598,14986)    zero Lmb pad (u32)
//  [14986,15374)    zero UpTb pad (u32)
//  [15374,15494)    Wi -> WiT
//  [15494,15686)    Wb -> WbT
//  [15686,18086)    Wo -> Wo2 (remap)
//  [18086,19058)    build_UT
__global__ __launch_bounds__(256)
void fat_setup(const float* __restrict__ uw_u, const float* __restrict__ uh_u,
               const float* __restrict__ ud_u, float* __restrict__ knots,
               const float* __restrict__ lu_ud, float* __restrict__ logdiag,
               const float* __restrict__ bo, float* __restrict__ bo2,
               const float* __restrict__ x, ushort_t* __restrict__ xb,
               const float* __restrict__ lower, ushort_t* __restrict__ Lmb,
               float* __restrict__ lq, float* __restrict__ zbias,
               ushort_t* __restrict__ zOddT, ushort_t* __restrict__ Wo2,
               const float* __restrict__ Wi, ushort_t* __restrict__ WiT,
               const float* __restrict__ Wb, ushort_t* __restrict__ WbT,
               const float* __restrict__ Wo,
               const float* __restrict__ upper, const int* __restrict__ perm,
               ushort_t* __restrict__ UpTb){
    __shared__ float sm[4];
    __shared__ float t[32][33];
    int b = blockIdx.x, tid = threadIdx.x;
    int tx = tid & 31, ty = tid >> 5;
    if(b < 4){
        int g = b*256 + tid;
        if(g >= 3*F_DIM) return;
        float* kb = knots + (size_t)g*43;
        float c[9], w[8];
        knots_from_u(uw_u + (size_t)g*8, c, w);
#pragma unroll
        for(int k=0;k<9;k++) kb[k]=c[k];
#pragma unroll
        for(int k=0;k<8;k++) kb[9+k]=w[k];
        knots_from_u(uh_u + (size_t)g*8, c, w);
#pragma unroll
        for(int k=0;k<9;k++) kb[17+k]=c[k];
#pragma unroll
        for(int k=0;k<8;k++) kb[26+k]=w[k];
        float dend = MIND_C + softplusf(DCONST_C);
        kb[34]=dend; kb[42]=dend;
        const float* ud = ud_u + (size_t)g*7;
#pragma unroll
        for(int k=0;k<7;k++) kb[35+k] = MIND_C + softplusf(ud[k]);
    } else if(b < 5){
        float s = 0.f;
        for(int k=tid; k<3*D_DIM; k+=256) s += __logf(softplusf(lu_ud[k]) + LUEPS_C);
#pragma unroll
        for(int o=32;o>0;o>>=1) s += __shfl_down(s, o);
        if((tid&63)==0) sm[tid>>6]=s;
        __syncthreads();
        if(tid==0) logdiag[0] = sm[0]+sm[1]+sm[2]+sm[3];
    } else if(b < 80){
        int idx = (b-5)*256 + tid;
        if(idx >= 3*OUT_DIM) return;
        int l = idx/OUT_DIM, n = idx%OUT_DIM;
        int f = n/23, j = n - 23*f;
        bo2[(size_t)l*WO24_ROWS + f*24 + j] = bo[idx];
    } else if(b < 9296){
        int idx = (b-80)*256 + tid;
        if(idx >= B_ROWS*D_PAD) return;
        int r = idx / D_PAD, c = idx - r*D_PAD;
        float v = (r<B_ROWS && c<D_DIM) ? x[(size_t)r*D_DIM+c] : 0.f;
        xb[idx] = f2bf(v);
    } else if(b < 14246){
        int lb = b - 9296;
        int l = lb/1650;
        int rem = lb - l*1650;
        int j = rem/3;
        int xb3 = rem - j*3;
        int k = xb3*256 + tid;
        if(k >= D_DIM) return;
        const float* lw = lower + (size_t)l*D_DIM*D_DIM;
        ushort_t* Lp = Lmb + (size_t)l*N_PAD_A*D_PAD;
        float lv = (j>k) ? lw[(size_t)j*D_DIM+k] : (j==k ? 1.f : 0.f);
        Lp[(size_t)j*D_PAD+k] = f2bf(lv);
    } else if(b < 14262){
        int p = (b-14246)*256 + tid;
        if(p < B_ROWS) lq[p] = 0.f;
    } else if(b < 14265){
        int p = (b-14262)*256 + tid;
        if(p < D_PAD) zbias[p] = 0.f;
    } else if(b < 14369){
        int p = (b-14265)*256 + tid;
        if(p < 13*2048){
            int row = 275 + p/2048, ci = p%2048;
            ((unsigned*)zOddT)[(size_t)row*2048 + ci] = 0u;
        }
    } else if(b < 14594){
        int p = (b-14369)*256 + tid;
        if(p < 57408){
            int l = p/19136, r2 = p%19136;
            int rl = r2/64, ci = r2%64;
            int row = (rl<275) ? rl*24+23 : 6600+(rl-275);
            ((unsigned*)Wo2)[((size_t)l*WO24_ROWS + row)*64 + ci] = 0u;
        }
    } else if(b < 14598){
        int p = (b-14594)*256 + tid;
        if(p < 897){
            int l = p/299, r = p%299;
            int idx2 = (r<275) ? r*24+23 : 6600+(r-275);
            bo2[(size_t)l*WO24_ROWS + idx2] = 0.f;
        }
    } else if(b < 14986){
        // Lmb pad zero: cols 550..575 for rows<550, full rows 550..639 (u32)
        int p = (b-14598)*256 + tid;
        if(p < PAD_TOTAL){
            int l = p/PAD_PER_LAYER, r = p%PAD_PER_LAYER;
            unsigned off;
            if(r < PAD_STRIP){ int j = r/13, ci = r%13; off = j*288u + 275u + ci; }
            else { int r2 = r-PAD_STRIP; int row = 550 + r2/288, ci = r2%288; off = row*288u + ci; }
            ((unsigned*)Lmb)[(size_t)l*LU_U32_PER_LAYER + off] = 0u;
        }
    } else if(b < 15374){
        int p = (b-14986)*256 + tid;
        if(p < PAD_TOTAL){
            int l = p/PAD_PER_LAYER, r = p%PAD_PER_LAYER;
            unsigned off;
            if(r < PAD_STRIP){ int j = r/13, ci = r%13; off = j*288u + 275u + ci; }
            else { int r2 = r-PAD_STRIP; int row = 550 + r2/288, ci = r2%288; off = row*288u + ci; }
            ((unsigned*)UpTb)[(size_t)l*LU_U32_PER_LAYER + off] = 0u;
        }
    } else if(b < 15494){
        int lb = b-15374;
        int z = lb/40, rem = lb%40, by = rem/10, bx = rem%10;
        tc_body(Wi, WiT, F_DIM, HID_DIM, F_PAD, HID_DIM,
                (long)F_DIM*HID_DIM, (long)F_PAD*HID_DIM, 0, bx, by, z, tx, ty, t);
    } else if(b < 15686){
        int lb = b-15494;
        int z = lb/16, rem = lb%16, by = rem/4, bx = rem%4;
        tc_body(Wb, WbT, HID_DIM, HID_DIM, HID_DIM, HID_DIM,
                (long)HID_DIM*HID_DIM, (long)HID_DIM*HID_DIM, 0, bx, by, z, tx, ty, t);
    } else if(b < 18086){
        int lb = b-15686;
        int z = lb/800, rem = lb%800, by = rem/4, bx = rem%4;
        tc_body(Wo, Wo2, HID_DIM, OUT_DIM, HID_DIM, OUT_PAD,
                (long)HID_DIM*OUT_DIM, (long)WO24_ROWS*HID_DIM, 1, bx, by, z, tx, ty, t);
    } else {
        int lb = b-18086;
        int l = lb/324, rem = lb%324, by = rem/18, bx = rem%18;
        const float* up = upper + (size_t)l*D_DIM*D_DIM;
        const float* udl = lu_ud + (size_t)l*D_DIM;
        const int* pm = perm + (size_t)l*D_DIM;
        ushort_t* Up = UpTb + (size_t)l*N_PAD_A*D_PAD;
        int j0 = bx*32, k0 = by*32;
#pragma unroll
        for(int i=0;i<32;i+=8){
            int j = j0+ty+i, k = k0+tx;
            float uv = 0.f;
            if(j<D_DIM && k<D_DIM){
                if(j<k)       uv = up[(size_t)j*D_DIM+k];
                else if(j==k) uv = softplusf(udl[k]) + LUEPS_C;
            }
            t[ty+i][tx] = uv;
        }
        __syncthreads();
#pragma unroll
        for(int i=0;i<32;i+=8){
            int k = k0+ty+i, j = j0+tx;
            if(k<D_DIM)
                Up[(size_t)pm[k]*D_PAD + j] = f2bf(t[tx][ty+i]);
        }
    }
}

// ------------------------------ bf16 MFMA gemm -----------------------------
template<int OUTBF>
__global__ __launch_bounds__(256)
void gemm_mfma(const ushort_t* __restrict__ A, const ushort_t* __restrict__ Bt,
               const float* __restrict__ bias, void* __restrict__ Cv,
               int M, int N, int Kpad, long sA, long sB, long sC){
    A  += (size_t)blockIdx.z*sA;
    Bt += (size_t)blockIdx.z*sB;
    __shared__ ushort_t As[128][72];
    __shared__ ushort_t Bs[128][72];
    int tid = threadIdx.x;
    int row0 = blockIdx.y*128, col0 = blockIdx.x*128;
    int wave = tid>>6, lane = tid&63;
    int wm = wave&1, wn = wave>>1;
    int lm = lane&15, quad = lane>>4;
    f32x4 acc[4][4] = {};
    for(int k0=0; k0<Kpad; k0+=64){
#pragma unroll
        for(int it=0; it<4; it++){
            int c = tid + it*256;
            int r = c>>3, c8 = (c&7)*8;
            *(ushort8*)&As[r][c8] = *(const ushort8*)(A + (size_t)(row0+r)*Kpad + k0 + c8);
            *(ushort8*)&Bs[r][c8] = *(const ushort8*)(Bt + (size_t)(col0+r)*Kpad + k0 + c8);
        }
        __syncthreads();
#pragma unroll
        for(int ks=0; ks<2; ks++){
            short8 af[4], bfr[4];
#pragma unroll
            for(int i=0;i<4;i++){
                af[i]  = *(const short8*)&As[wm*64 + i*16 + lm][ks*32 + quad*8];
                bfr[i] = *(const short8*)&Bs[wn*64 + i*16 + lm][ks*32 + quad*8];
            }
#pragma unroll
            for(int i=0;i<4;i++)
#pragma unroll
                for(int j=0;j<4;j++)
                    acc[i][j] = __builtin_amdgcn_mfma_f32_16x16x32_bf16(af[i], bfr[j], acc[i][j], 0, 0, 0);
        }
        __syncthreads();
    }
#pragma unroll
    for(int i=0;i<4;i++){
        int rbase = row0 + wm*64 + i*16 + quad*4;
#pragma unroll
        for(int j=0;j<4;j++){
            int gc = col0 + wn*64 + j*16 + lm;
            if(gc >= N) continue;
            float bv = bias[gc];
#pragma unroll
            for(int r=0;r<4;r++){
                int gr = rbase + r;
                float v = acc[i][j][r] + bv;
                if(OUTBF) ((ushort_t*)Cv + (size_t)blockIdx.z*sC)[(size_t)gr*N+gc] = f2bf(v);
                else      ((float*)Cv + (size_t)blockIdx.z*sC)[(size_t)gr*N+gc] = v;
            }
        }
    }
}

// ------------------------------ fused resnet -------------------------------
// 16 rows/block, grid 256. No LDS weight staging (L2->reg, prefetched).
__global__ __launch_bounds__(256)
void resnet_fused(const ushort_t* __restrict__ identb,
                  const ushort_t* __restrict__ WiT,
                  const float* __restrict__ bi,
                  const ushort_t* __restrict__ WbT,
                  const float* __restrict__ bb,
                  ushort_t* __restrict__ tb){
    __shared__ ushort_t As2[16][136];
    int tid = threadIdx.x, wave = tid>>6, lane = tid&63;
    int lm = lane&15, quad = lane>>4;
    int r0 = blockIdx.x*16;
    int arow = r0 + lm;
    f32x4 cur[2] = {};
    f32x4 tsv[2];
    for(int k0=0; k0<F_PAD; k0+=64){
        const ushort_t* ap = identb + (size_t)arow*F_PAD + k0 + quad*8;
        short8 af0 = *(const short8*)(ap);
        short8 af1 = *(const short8*)(ap + 32);
#pragma unroll
        for(int jj=0;jj<2;jj++){
            int n = (wave*2+jj)*16 + lm;
            const ushort_t* wp = WiT + (size_t)n*F_PAD + k0 + quad*8;
            short8 b0 = *(const short8*)(wp);
            short8 b1 = *(const short8*)(wp + 32);
            cur[jj] = __builtin_amdgcn_mfma_f32_16x16x32_bf16(af0, b0, cur[jj], 0, 0, 0);
            cur[jj] = __builtin_amdgcn_mfma_f32_16x16x32_bf16(af1, b1, cur[jj], 0, 0, 0);
        }
    }
#pragma unroll
    for(int jj=0;jj<2;jj++){
        float bv = bi[(wave*2+jj)*16 + lm];
#pragma unroll
        for(int r=0;r<4;r++) cur[jj][r] += bv;
        tsv[jj] = cur[jj];
    }
    short8 wA[2][4], wB[2][4];
#pragma unroll
    for(int jj=0;jj<2;jj++){
        int n = (wave*2+jj)*16 + lm;
        const ushort_t* wp = WbT + (size_t)n*128 + quad*8;
#pragma unroll
        for(int ks=0;ks<4;ks++) wA[jj][ks] = *(const short8*)(wp + ks*32);
    }
#pragma unroll
    for(int st=0; st<4; st++){
        __syncthreads();
#pragma unroll
        for(int jj=0;jj<2;jj++)
#pragma unroll
            for(int r=0;r<4;r++)
                As2[quad*4 + r][(wave*2+jj)*16 + lm] = f2bf(fmaxf(cur[jj][r], 0.f));
        if(st < 3){
#pragma unroll
            for(int jj=0;jj<2;jj++){
                int n = (wave*2+jj)*16 + lm;
                const ushort_t* wp = WbT + (size_t)(st+1)*128*128 + (size_t)n*128 + quad*8;
#pragma unroll
                for(int ks=0;ks<4;ks++){
                    if(st & 1) wA[jj][ks] = *(const short8*)(wp + ks*32);
                    else       wB[jj][ks] = *(const short8*)(wp + ks*32);
                }
            }
        }
        __syncthreads();
        short8 af[4];
#pragma unroll
        for(int ks=0;ks<4;ks++) af[ks] = *(const short8*)&As2[lm][ks*32 + quad*8];
        f32x4 acc[2] = {};
#pragma unroll
        for(int ks=0;ks<4;ks++){
#pragma unroll
            for(int jj=0;jj<2;jj++){
                short8 bf = (st & 1) ? wB[jj][ks] : wA[jj][ks];
                acc[jj] = __builtin_amdgcn_mfma_f32_16x16x32_bf16(af[ks], bf, acc[jj], 0, 0, 0);
            }
        }
#pragma unroll
        for(int jj=0;jj<2;jj++){
            float bv = bb[st*128 + (wave*2+jj)*16 + lm];
#pragma unroll
            for(int r=0;r<4;r++) acc[jj][r] += bv;
        }
        if(st==1 || st==3){
#pragma unroll
            for(int jj=0;jj<2;jj++){
#pragma unroll
                for(int r=0;r<4;r++) acc[jj][r] += tsv[jj][r];
                tsv[jj] = acc[jj];
            }
        }
#pragma unroll
        for(int jj=0;jj<2;jj++) cur[jj] = acc[jj];
    }
#pragma unroll
    for(int jj=0;jj<2;jj++)
#pragma unroll
        for(int r=0;r<4;r++)
            tb[(size_t)(r0 + quad*4 + r)*HID_DIM + (wave*2+jj)*16 + lm] = f2bf(cur[jj][r]);
}

// ------------- fat zident: zodd_transpose + ident_spline -------------------
__global__ __launch_bounds__(320)
void zident(const float* __restrict__ z2, const float* __restrict__ knots,
            int layer, float* __restrict__ z2oddT,
            ushort_t* __restrict__ identb, float* __restrict__ lq){
    __shared__ float s[32][65];
    __shared__ float sm[5];
    int b = blockIdx.x, tid = threadIdx.x;
    if(b < 576){
        int r0 = (b & 63)*64, f0 = (b >> 6)*32;
        int f = tid & 31, rb = tid >> 5;
        if(tid < 256){
#pragma unroll
            for(int rr=0; rr<8; rr++){
                int r = rb + rr*8;
                int fg = f0 + f;
                float v = (fg < F_DIM) ? z2[(size_t)(r0+r)*D_DIM + 2*fg + 1] : 0.f;
                s[f][r] = v;
            }
        }
        __syncthreads();
        if(tid < 256){
            int lane = tid & 63, fb = tid >> 6;
#pragma unroll
            for(int ff=0; ff<8; ff++){
                int fo = fb + ff*4;
                z2oddT[(size_t)(f0+fo)*B_ROWS + r0 + lane] = s[fo][lane];
            }
        }
    } else {
        int row = b - 576;
        float ldv = 0.f;
        if(tid < F_DIM){
            const float* kb = knots + ((size_t)(layer*F_DIM + tid))*43;
            float x = z2[(size_t)row*D_DIM + 2*tid];
            float o, l;
            rqs_inv(x, kb, kb+9, kb+17, kb+26, kb+34, o, l);
            identb[(size_t)row*F_PAD + tid] = f2bf(o);
            ldv = l;
        } else {
            identb[(size_t)row*F_PAD + tid] = 0;
        }
        float v = ldv;
#pragma unroll
        for(int o=32;o>0;o>>=1) v += __shfl_down(v, o);
        if((tid&63)==0) sm[tid>>6]=v;
        __syncthreads();
        if(tid==0) lq[row] += sm[0]+sm[1]+sm[2]+sm[3]+sm[4];
    }
}

// ----------------------- fused Wo gemm + trans spline ----------------------
__global__ __launch_bounds__(256, 4)
void wo_spline(const ushort_t* __restrict__ tb,
               const ushort_t* __restrict__ Wo2,
               const float* __restrict__ bo2,
               const float* __restrict__ z2oddT,
               ushort_t* __restrict__ zOddT,
               float* __restrict__ ldpart){
    __shared__ __align__(16) char smem[128*51*4];
    __shared__ float ldred[128];
    ushort_t (*As)[72] = (ushort_t(*)[72])smem;                 // 128x64 bf16
    ushort_t (*Bs)[72] = (ushort_t(*)[72])(smem + 128*72*2);    // 48x64 bf16
    float (*P)[51] = (float(*)[51])smem;                        // 128x51 f32
    int tid = threadIdx.x;
    int flat = blockIdx.y*WO_GX + blockIdx.x;
    int flat2 = (flat & 7)*(WO_GX*32/8) + (flat >> 3);          // 4416 = 8*552
    int cbl = flat2 % WO_GX;          // 0..137
    int rbl = flat2 / WO_GX;          // 0..31
    int row0 = rbl*128, col0 = cbl*48;
    int wave = tid>>6, lane = tid&63;
    int lm = lane&15, quad = lane>>4;
    f32x4 acc[2][3] = {};
    for(int k0=0; k0<HID_DIM; k0+=64){
#pragma unroll
        for(int it=0; it<4; it++){
            int c = tid + it*256;
            int r = c>>3, c8 = (c&7)*8;
            *(ushort8*)&As[r][c8] = *(const ushort8*)(tb + (size_t)(row0+r)*HID_DIM + k0 + c8);
        }
#pragma unroll
        for(int it=0; it<2; it++){
            int v = tid + it*256;
            if(v < 384){
                int n = v>>3, c8 = (v&7)*8;
                *(ushort8*)&Bs[n][c8] = *(const ushort8*)(Wo2 + (size_t)(col0+n)*HID_DIM + k0 + c8);
            }
        }
        __syncthreads();
#pragma unroll
        for(int ks=0; ks<2; ks++){
            short8 af[2], bfr[3];
#pragma unroll
            for(int i=0;i<2;i++)
                af[i]  = *(const short8*)&As[wave*32 + i*16 + lm][ks*32 + quad*8];
#pragma unroll
            for(int j=0;j<3;j++)
                bfr[j] = *(const short8*)&Bs[j*16 + lm][ks*32 + quad*8];
#pragma unroll
            for(int i=0;i<2;i++)
#pragma unroll
                for(int j=0;j<3;j++)
                    acc[i][j] = __builtin_amdgcn_mfma_f32_16x16x32_bf16(af[i], bfr[j], acc[i][j], 0, 0, 0);
        }
        __syncthreads();
    }
#pragma unroll
    for(int j=0;j<3;j++){
        int cl = j*16 + lm;
        float bv = bo2[col0 + cl];
#pragma unroll
        for(int i=0;i<2;i++){
            int rl = wave*32 + i*16 + quad*4;
#pragma unroll
            for(int r=0;r<4;r++) P[rl+r][cl] = acc[i][j][r] + bv;
        }
    }
    __syncthreads();
    // One spline per thread: row = tid&127, feat = tid>>7.
    int row = tid & 127, feat = tid >> 7;
    int fg = cbl*2 + feat;
    float ldsum = 0.f;
    const float dend = MIND_C + softplusf(DCONST_C);
    if(fg < F_DIM){
        const float* q = &P[row][feat*24];
        float xv = z2oddT[(size_t)fg*B_ROWS + row0 + row];
        bool inside = (xv >= -TB_C) && (xv <= TB_C);
        float xi = fminf(fmaxf(xv, -TB_C), TB_C);
        // height knots (softmax over q[8..15]) -> bin index
        float eh[8];
        float mh = -1e30f, sh = 0.f;
#pragma unroll
        for(int k=0;k<8;k++){ float u = q[8+k]*RSQRT_HID; eh[k]=u; mh=fmaxf(mh,u); }
#pragma unroll
        for(int k=0;k<8;k++){ eh[k] = __expf(eh[k]-mh); sh += eh[k]; }
        float invh = (1.f - MINB_C*8.f)/sh;
        int idx = 0;
        {
            float cum = 0.f;
#pragma unroll
            for(int k=0;k<7;k++){
                cum += MINB_C + eh[k]*invh;
                float ck = 2.f*TB_C*cum - TB_C;
                idx += (xi >= ck) ? 1 : 0;
            }
        }
        float ich = -TB_C, ihh = 0.f;
        {
            float cum = 0.f, cprev = -TB_C;
#pragma unroll
            for(int k=0;k<8;k++){
                cum += MINB_C + eh[k]*invh;
                float ck = (k==7) ? TB_C : (2.f*TB_C*cum - TB_C);
                if(idx==k){ ich = cprev; ihh = ck - cprev; }
                cprev = ck;
            }
        }
        // width knots
        float ew[8];
        float mw = -1e30f, sw = 0.f;
#pragma unroll
        for(int k=0;k<8;k++){ float u = q[k]*RSQRT_HID; ew[k]=u; mw=fmaxf(mw,u); }
#pragma unroll
        for(int k=0;k<8;k++){ ew[k] = __expf(ew[k]-mw); sw += ew[k]; }
        float invw = (1.f - MINB_C*8.f)/sw;
        float icw = -TB_C, iww = 0.f;
        {
            float cum = 0.f, cprev = -TB_C;
#pragma unroll
            for(int k=0;k<8;k++){
                cum += MINB_C + ew[k]*invw;
                float ck = (k==7) ? TB_C : (2.f*TB_C*cum - TB_C);
                if(idx==k){ icw = cprev; iww = ck - cprev; }
                cprev = ck;
            }
        }
        float d0 = (idx==0) ? dend : (MIND_C + softplusf(q[15+idx]));
        float d1 = (idx==7) ? dend : (MIND_C + softplusf(q[16+idx]));
        float delta = ihh/iww;
        float t  = xi - ich;
        float s  = d0 + d1 - 2.f*delta;
        float a  = t*s + ihh*(delta - d0);
        float b  = ihh*d0 - t*s;
        float c  = -delta*t;
        float disc = fmaxf(b*b - 4.f*a*c, 0.f);
        float root = 2.f*c / (-b - sqrtf(disc));
        float o  = root*iww + icw;
        float tm = root*(1.f-root);
        float den  = delta + s*tm;
        float dnum = delta*delta*(d1*root*root + 2.f*delta*tm + d0*(1.f-root)*(1.f-root));
        float l = 2.f*__logf(den) - __logf(dnum);
        zOddT[(size_t)fg*B_ROWS + row0 + row] = f2bf(inside ? o : xv);
        ldsum = inside ? l : 0.f;
    }
    if(tid >= 128) ldred[tid-128] = ldsum;
    __syncthreads();
    if(tid < 128) ldpart[(size_t)cbl*B_ROWS + row0 + tid] = ldsum + ldred[tid];
}

// --------------------- interleave even/odd z into znb ----------------------
// LAST=0: znb[row][2f] = identb[row][f]; znb[row][2f+1] = zOddT[f][row];
//         lq[r] += sum_cb ldpart.
// LAST=1: skip znb writes; compute out[row] = lq + ld - const - gaussian
//         directly (bf16 values bit-identical to what finalize would read).
template<int LAST>
__global__ __launch_bounds__(256)
void interleave_z(const ushort_t* __restrict__ identb,
                  const ushort_t* __restrict__ zOddT,
                  const float* __restrict__ ldpart,
                  ushort_t* __restrict__ znb,
                  float* __restrict__ lq,
                  const float* __restrict__ loc,
                  const float* __restrict__ lsc,
                  const float* __restrict__ logdiag,
                  float* __restrict__ out){
    __shared__ ushort_t s[FP_HALF][34];
    __shared__ float lqv[32];
    int r0 = blockIdx.x*32;
    int tid = threadIdx.x;
#pragma unroll
    for(int i=0;i<36;i++){
        int idx = tid + i*256;
        int f = idx>>5, r = idx&31;
        s[f][r] = zOddT[(size_t)f*B_ROWS + r0 + r];
    }
    __syncthreads();
    if(tid < 32){
        float acc = 0.f;
        for(int cb=0; cb<WO_GX; cb++)
            acc += ldpart[(size_t)cb*B_ROWS + r0 + tid];
        if(LAST) lqv[tid] = lq[r0 + tid] + acc;
        else     lq[r0 + tid] += acc;
    }
    if(LAST) __syncthreads();
    int wv = tid>>6, lane = tid&63;
#pragma unroll
    for(int k=0;k<8;k++){
        int r = wv + k*4;
        const ushort_t* idr = identb + (size_t)(r0+r)*F_PAD;
        if(!LAST){
            unsigned* orow = (unsigned*)(znb + (size_t)(r0+r)*D_PAD);
#pragma unroll
            for(int c=0;c<5;c++){
                int f = lane + c*64;
                if(f < FP_HALF){
                    unsigned lo = idr[f];
                    unsigned hi = s[f][r];
                    orow[f] = lo | (hi<<16);
                }
            }
        } else {
            float fsum = 0.f;
#pragma unroll
            for(int c=0;c<5;c++){
                int f = lane + c*64;
                if(f < F_DIM){
                    float le = lsc[2*f], lo2 = lsc[2*f+1];
                    float de = (bf2f(idr[f])  - loc[2*f])  *__expf(-le);
                    float dо = (bf2f(s[f][r]) - loc[2*f+1])*__expf(-lo2);
                    fsum += le + 0.5f*de*de + lo2 + 0.5f*dо*dо;
                }
            }
#pragma unroll
            for(int o=32;o>0;o>>=1) fsum += __shfl_down(fsum, o);
            if(lane==0)
                out[r0+r] = lqv[r] + logdiag[0] - 275.f*1.8378770664f - fsum;
        }
    }
}

// ---------------------------------------------------------------------------

extern "C" void kernel_launch(void* const* d_in, const int* in_sizes, int n_in,
                              void* d_out, int out_size, void* d_ws, size_t ws_size,
                              hipStream_t stream){
    const float* x        = (const float*)d_in[0];
    const float* loc      = (const float*)d_in[1];
    const float* lsc      = (const float*)d_in[2];
    const float* Wi       = (const float*)d_in[3];
    const float* bi       = (const float*)d_in[4];
    const float* Wb       = (const float*)d_in[5];
    const float* bb       = (const float*)d_in[6];
    const float* Wo       = (const float*)d_in[7];
    const float* bo       = (const float*)d_in[8];
    const float* uw_u     = (const float*)d_in[9];
    const float* uh_u     = (const float*)d_in[10];
    const float* ud_u     = (const float*)d_in[11];
    const float* lu_lower = (const float*)d_in[12];
    const float* lu_upper = (const float*)d_in[13];
    const float* lu_ud    = (const float*)d_in[14];
    const float* lu_b     = (const float*)d_in[15];
    const int*   perms    = (const int*)d_in[16];
    float* out = (float*)d_out;

    char* base = (char*)d_ws;
    size_t off = 0;
    auto alloc = [&](size_t bytes)->char*{
        char* p = base + off;
        off += (bytes + 255) & ~(size_t)255;
        return p;
    };
    float* lq      = (float*)alloc(B_ROWS*4);
    float* zbias   = (float*)alloc(D_PAD*4);
    float* logdiag = (float*)alloc(64*4);
    float* knots   = (float*)alloc((size_t)3*F_DIM*43*4);
    float* z2      = (float*)alloc((size_t)B_ROWS*D_DIM*4);
    float* z2oddT  = (float*)alloc((size_t)FP_HALF*B_ROWS*4);
    float* ldpart  = (float*)alloc((size_t)WO_GX*B_ROWS*4);
    float* bo2     = (float*)alloc((size_t)3*WO24_ROWS*4);
    ushort_t* xb   = (ushort_t*)alloc((size_t)B_ROWS*D_PAD*2);
    ushort_t* zbf0 = (ushort_t*)alloc((size_t)B_ROWS*D_PAD*2);
    ushort_t* zbf1 = (ushort_t*)alloc((size_t)B_ROWS*D_PAD*2);
    ushort_t* zOddT= (ushort_t*)alloc((size_t)FP_HALF*B_ROWS*2);
    ushort_t* Lmb  = (ushort_t*)alloc((size_t)3*N_PAD_A*D_PAD*2);
    ushort_t* UpTb = (ushort_t*)alloc((size_t)3*N_PAD_A*D_PAD*2);
    ushort_t* Apb  = (ushort_t*)alloc((size_t)3*N_PAD_A*D_PAD*2);
    ushort_t* identb=(ushort_t*)alloc((size_t)B_ROWS*F_PAD*2);
    ushort_t* tb   = (ushort_t*)alloc((size_t)B_ROWS*HID_DIM*2);
    ushort_t* WiT  = (ushort_t*)alloc((size_t)3*HID_DIM*F_PAD*2);
    ushort_t* WbT  = (ushort_t*)alloc((size_t)3*4*HID_DIM*HID_DIM*2);
    ushort_t* Wo2  = (ushort_t*)alloc((size_t)3*WO24_ROWS*HID_DIM*2);

    fat_setup<<<dim3(19058), dim3(256), 0, stream>>>(
        uw_u, uh_u, ud_u, knots, lu_ud, logdiag, bo, bo2,
        x, xb, lu_lower, Lmb, lq, zbias, zOddT, Wo2,
        Wi, WiT, Wb, WbT, Wo, lu_upper, perms, UpTb);

    gemm_mfma<1><<<dim3(5, 5, 3), dim3(256), 0, stream>>>(
        Lmb, UpTb, zbias, Apb, N_PAD_A, D_PAD, D_PAD,
        (long)N_PAD_A*D_PAD, (long)N_PAD_A*D_PAD, (long)N_PAD_A*D_PAD);

    const ushort_t* zcur_b = xb;
    ushort_t* zbf[2] = {zbf0, zbf1};
    int zi = 0;

    for(int it=0; it<3; ++it){
        int i = 2 - it;

        gemm_mfma<0><<<dim3(N_PAD_A/128, B_ROWS/128), dim3(256), 0, stream>>>(
            zcur_b, Apb + (size_t)i*N_PAD_A*D_PAD, lu_b + (size_t)i*D_DIM,
            z2, B_ROWS, D_DIM, D_PAD, 0, 0, 0);

        zident<<<dim3(576 + B_ROWS), dim3(320), 0, stream>>>(
            z2, knots, i, z2oddT, identb, lq);

        resnet_fused<<<dim3(B_ROWS/16), dim3(256), 0, stream>>>(
            identb, WiT + (size_t)i*HID_DIM*F_PAD, bi + (size_t)i*HID_DIM,
            WbT + (size_t)i*4*HID_DIM*HID_DIM, bb + (size_t)i*4*HID_DIM, tb);

        wo_spline<<<dim3(WO_GX, B_ROWS/128), dim3(256), 0, stream>>>(
            tb, Wo2 + (size_t)i*WO24_ROWS*HID_DIM, bo2 + (size_t)i*WO24_ROWS,
            z2oddT, zOddT, ldpart);

        if(it < 2){
            interleave_z<0><<<dim3(B_ROWS/32), dim3(256), 0, stream>>>(
                identb, zOddT, ldpart, zbf[zi], lq,
                nullptr, nullptr, nullptr, nullptr);
        } else {
            interleave_z<1><<<dim3(B_ROWS/32), dim3(256), 0, stream>>>(
                identb, zOddT, ldpart, zbf[zi], lq,
                loc, lsc, logdiag, out);
        }

        zcur_b = zbf[zi];
        zi ^= 1;
    }
}